// Round 13
// baseline (1556.426 us; speedup 1.0000x reference)
//
#include <hip/hip_runtime.h>

#define DEVI __device__ __forceinline__

typedef short bf16x8 __attribute__((ext_vector_type(8)));
typedef float f32x4 __attribute__((ext_vector_type(4)));
typedef unsigned short u16;
typedef unsigned short u16x8 __attribute__((ext_vector_type(8)));
typedef unsigned short u16x4 __attribute__((ext_vector_type(4)));

enum { EPI_MLP = 0, EPI_DISTQ = 1, EPI_NEGTRI = 2 };

#define KLOG2E_T 28.853900817779268f /* log2(e)/TEMP */
#define QSCALE 1846.6496523378733f   /* KLOG2E_T * 64 */
#define INVQ 0.015625f               /* 1/64 */
#define PSLOTS 80                    /* 0..7 row, 8..71 pos-col, 72..79 neg-col */

// ---------- small helpers ----------
DEVI u16 f2bf(float f) {
  unsigned u = __float_as_uint(f);
  return (u16)((u + 0x7FFFu + ((u >> 16) & 1u)) >> 16);
}
DEVI float bf2f(u16 h) { return __uint_as_float(((unsigned)h) << 16); }
DEVI float seluf(float x) {
  return x > 0.f ? 1.0507009873554805f * x : 1.7580993408473766f * expm1f(x);
}
DEVI void gload16(const void* g, void* l) {
  __builtin_amdgcn_global_load_lds(
      (const __attribute__((address_space(1))) unsigned*)g,
      (__attribute__((address_space(3))) unsigned*)l, 16, 0, 0);
}
DEVI void lse_comb(float& m, float& s, float m2, float s2) {
  float M = fmaxf(m, m2);
  s = s * exp2f(m - M) + s2 * exp2f(m2 - M);
  m = M;
}
DEVI size_t triblk(int I, int J) { return ((size_t)I * (I + 1) / 2 + J) * 4096; }

// ---------- GEMM: C = A * B^T, split-bf16 (hi+lo, 3 MFMA); hoisted-pointer staging ----------
template <int BM, int BN, int WM, int WN, int EPI>
__global__ __launch_bounds__(WM* WN * 64) void gemm_k(
    const u16* __restrict__ Ahi, const u16* __restrict__ Alo, int lda,
    const u16* __restrict__ Bhi, const u16* __restrict__ Blo, int ldb, int K,
    float* __restrict__ Cf, int ldc,
    const float* __restrict__ bias, int act, u16* __restrict__ Ohi,
    u16* __restrict__ Olo, int ldo,
    const float* __restrict__ xN2, const float* __restrict__ yN2,
    u16* __restrict__ Cq) {
  constexpr int NW = WM * WN;
  constexpr int FM = BM / (WM * 16), FN = BN / (WN * 16);
  constexpr int IA = BM / (16 * NW), IB = BN / (16 * NW);
  const int tid = threadIdx.x, lane = tid & 63, wave = tid >> 6;
  int bm0, bn0;
  if constexpr (EPI == EPI_DISTQ) {
    // L2 super-tile swizzle: XCD (bid&7) walks 8x8-block super-tiles (~2MB set -> L2-fit)
    int bid = (int)blockIdx.x;
    int xcd = bid & 7, p = bid >> 3;
    int st = (p >> 6) * 8 + xcd;
    int r8 = (p >> 3) & 7, c8 = p & 7;
    bm0 = ((st >> 3) * 8 + r8) * 128;
    bn0 = ((st & 7) * 8 + c8) * 128;
  } else if constexpr (EPI == EPI_NEGTRI) {
    // compact lower block-triangle: 2080 tiles of 128^2
    int t = (int)blockIdx.x;
    int a = (int)((sqrtf(8.f * (float)t + 1.f) - 1.f) * 0.5f);
    while ((a + 1) * (a + 2) / 2 <= t) ++a;
    while (a * (a + 1) / 2 > t) --a;
    int b = t - a * (a + 1) / 2;
    bm0 = a * 128;
    bn0 = b * 128;
  } else {
    bm0 = blockIdx.y * BM;
    bn0 = blockIdx.x * BN;
  }
  const int wr = (wave / WN) * (FM * 16), wc = (wave % WN) * (FN * 16);
  __shared__ __align__(16) u16 AsH[BM * 32];
  __shared__ __align__(16) u16 BsH[BN * 32];
  __shared__ __align__(16) u16 AsL[BM * 32];
  __shared__ __align__(16) u16 BsL[BN * 32];
  // hoisted staging pointers: stepped +32 per k-iter
  const int srow = lane >> 2, scol = (lane & 3) * 8;
  const u16 *pAh[IA], *pAl[IA], *pBh[IB], *pBl[IB];
  int lA[IA], lB[IB];
#pragma unroll
  for (int t = 0; t < IA; ++t) {
    int r = (wave * IA + t) * 16;
    pAh[t] = Ahi + (size_t)(bm0 + r + srow) * lda + scol;
    pAl[t] = Alo + (size_t)(bm0 + r + srow) * lda + scol;
    lA[t] = r * 32;
  }
#pragma unroll
  for (int t = 0; t < IB; ++t) {
    int r = (wave * IB + t) * 16;
    pBh[t] = Bhi + (size_t)(bn0 + r + srow) * ldb + scol;
    pBl[t] = Blo + (size_t)(bn0 + r + srow) * ldb + scol;
    lB[t] = r * 32;
  }
  f32x4 acc[FM][FN] = {};
  const int fr = lane & 15, ko = (lane >> 4) * 8;
  for (int k0 = 0; k0 < K; k0 += 32) {
#pragma unroll
    for (int t = 0; t < IA; ++t) {
      gload16(pAh[t], AsH + lA[t]); pAh[t] += 32;
      gload16(pAl[t], AsL + lA[t]); pAl[t] += 32;
    }
#pragma unroll
    for (int t = 0; t < IB; ++t) {
      gload16(pBh[t], BsH + lB[t]); pBh[t] += 32;
      gload16(pBl[t], BsL + lB[t]); pBl[t] += 32;
    }
    __syncthreads();
    bf16x8 ah[FM], bh[FN], al[FM], bl[FN];
#pragma unroll
    for (int m = 0; m < FM; ++m) ah[m] = *(const bf16x8*)&AsH[(wr + m * 16 + fr) * 32 + ko];
#pragma unroll
    for (int n = 0; n < FN; ++n) bh[n] = *(const bf16x8*)&BsH[(wc + n * 16 + fr) * 32 + ko];
#pragma unroll
    for (int m = 0; m < FM; ++m) al[m] = *(const bf16x8*)&AsL[(wr + m * 16 + fr) * 32 + ko];
#pragma unroll
    for (int n = 0; n < FN; ++n) bl[n] = *(const bf16x8*)&BsL[(wc + n * 16 + fr) * 32 + ko];
#pragma unroll
    for (int m = 0; m < FM; ++m)
#pragma unroll
      for (int n = 0; n < FN; ++n) {
        acc[m][n] = __builtin_amdgcn_mfma_f32_16x16x32_bf16(ah[m], bh[n], acc[m][n], 0, 0, 0);
        acc[m][n] = __builtin_amdgcn_mfma_f32_16x16x32_bf16(al[m], bh[n], acc[m][n], 0, 0, 0);
        acc[m][n] = __builtin_amdgcn_mfma_f32_16x16x32_bf16(ah[m], bl[n], acc[m][n], 0, 0, 0);
      }
    __syncthreads();
  }
#pragma unroll
  for (int m = 0; m < FM; ++m)
#pragma unroll
    for (int n = 0; n < FN; ++n)
#pragma unroll
      for (int q = 0; q < 4; ++q) {
        int row = bm0 + wr + m * 16 + (lane >> 4) * 4 + q;
        int col = bn0 + wc + n * 16 + fr;
        float v = acc[m][n][q];
        if constexpr (EPI == EPI_MLP) {
          v += bias[col];
          if (act) v = seluf(v);
          u16 h = f2bf(v);
          size_t idx = (size_t)row * ldo + col;
          Ohi[idx] = h;
          Olo[idx] = f2bf(v - bf2f(h));
          if (Cf) Cf[(size_t)row * ldc + col] = v;
        } else if constexpr (EPI == EPI_DISTQ) {
          float d2 = fmaxf(xN2[row] + yN2[col] - 2.f * v, 0.f);
          float qf = fminf(QSCALE * sqrtf(d2), 65535.f);
          Cq[(size_t)row * 8192 + col] = (u16)__float2uint_rn(qf);
        } else {  // EPI_NEGTRI
          int bI = row >> 6, bJ = col >> 6;
          if (bJ <= bI) {
            float d2 = fmaxf(xN2[row] + yN2[col] - 2.f * v, 0.f);
            float qf = fminf(QSCALE * sqrtf(d2), 65535.f);
            u16 qu = (u16)__float2uint_rn(qf);
            if (row == col) qu = 65535;
            Cq[triblk(bI, bJ) + (row & 63) * 64 + (col & 63)] = qu;
          }
        }
      }
}

// ---------- shared LSE micro-op ----------
DEVI void lse16(const u16x8& qa, const u16x8& qb, const float* w,
                float& m, float& s) {
  f32x4 w0 = *(const f32x4*)w;
  f32x4 w1 = *(const f32x4*)(w + 4);
  f32x4 w2 = *(const f32x4*)(w + 8);
  f32x4 w3 = *(const f32x4*)(w + 12);
  float v[16];
#pragma unroll
  for (int e = 0; e < 4; ++e) {
    v[e] = fmaf((float)qa[e], -INVQ, -w0[e]);
    v[4 + e] = fmaf((float)qa[4 + e], -INVQ, -w1[e]);
    v[8 + e] = fmaf((float)qb[e], -INVQ, -w2[e]);
    v[12 + e] = fmaf((float)qb[4 + e], -INVQ, -w3[e]);
  }
  float mx = v[0];
#pragma unroll
  for (int e = 1; e < 16; ++e) mx = fmaxf(mx, v[e]);
  float ac = 0.f;
#pragma unroll
  for (int e = 0; e < 16; ++e) ac += exp2f(v[e] - mx);
  lse_comb(m, s, mx, ac);
}

// ---------- Sinkhorn row-LSE: stripe of 64 rows, EIGHTH of j-range ----------
// use_comb=0: weights read from global cpos/cneg vectors (iter 1, zeroed)
// use_comb=1: weights combined in-block from Pm/Ps slots 8..71 (cpos), 72..79 (cneg)
__global__ __launch_bounds__(256) void sink_k(
    const u16* __restrict__ DqPos, const u16* __restrict__ DqTri,
    const float* __restrict__ wpos, const float* __restrict__ wneg,
    float* __restrict__ Pm, float* __restrict__ Ps, int use_comb) {
  const int tid = threadIdx.x;
  const int I = blockIdx.y, q8 = blockIdx.x;
  __shared__ __align__(16) u16 stg[4096];
  __shared__ float Cm[64][12], Cs[64][12];
  __shared__ float wpL[1024], wnL[1024];
  if (use_comb) {
    for (int t = tid; t < 1024; t += 256) {
      int j = q8 * 1024 + t;
      float m = Pm[(size_t)8 * 8192 + j], s = Ps[(size_t)8 * 8192 + j];
      for (int b = 9; b < 72; ++b)
        lse_comb(m, s, Pm[(size_t)b * 8192 + j], Ps[(size_t)b * 8192 + j]);
      wpL[t] = m + log2f(s);
      float m2 = Pm[(size_t)72 * 8192 + j], s2 = Ps[(size_t)72 * 8192 + j];
      for (int b = 73; b < 80; ++b)
        lse_comb(m2, s2, Pm[(size_t)b * 8192 + j], Ps[(size_t)b * 8192 + j]);
      wnL[t] = m2 + log2f(s2);
    }
  } else {
    for (int t = tid; t < 1024; t += 256) {
      int j = q8 * 1024 + t;
      wpL[t] = wpos[j];
      wnL[t] = wneg[j];
    }
  }
  __syncthreads();
  const int rn = tid >> 2, cn = (tid & 3) * 16;  // natural org: 4 thr/row
  const int p2 = tid & 31, g8 = tid >> 5;        // transposed org
  float mA = -3.0e38f, sA = 0.f;
  float mB0 = -3.0e38f, sB0 = 0.f, mB1 = -3.0e38f, sB1 = 0.f;
  const int sw = (rn & 7) << 3;

  {
    const size_t rowbase = (size_t)(I * 64 + rn) * 8192;
    for (int jc = 0; jc < 16; ++jc) {
      int jl = jc * 64 + cn;
      u16x8 qa = *(const u16x8*)&DqPos[rowbase + q8 * 1024 + jl];
      u16x8 qb = *(const u16x8*)&DqPos[rowbase + q8 * 1024 + jl + 8];
      lse16(qa, qb, wpL + jl, mA, sA);
    }
  }
  for (int Jb = q8 * 16; Jb < q8 * 16 + 16; ++Jb) {
    const int jl = (Jb - q8 * 16) * 64;
    if (Jb <= I) {
      const u16* blk = DqTri + triblk(I, Jb);
      u16x8 qa = *(const u16x8*)&blk[rn * 64 + cn];
      u16x8 qb = *(const u16x8*)&blk[rn * 64 + cn + 8];
      lse16(qa, qb, wnL + jl + cn, mA, sA);
    } else {
      const u16* blk = DqTri + triblk(Jb, I);
      u16x8 qa = *(const u16x8*)&blk[rn * 64 + cn];
      u16x8 qb = *(const u16x8*)&blk[rn * 64 + cn + 8];
      *(u16x8*)&stg[rn * 64 + (cn ^ sw)] = qa;
      *(u16x8*)&stg[rn * 64 + ((cn + 8) ^ sw)] = qb;
      __syncthreads();
      float v0[8], v1[8];
#pragma unroll
      for (int cc = 0; cc < 8; ++cc) {
        int sj = cc * 8 + g8;
        unsigned wq = *(const unsigned*)&stg[sj * 64 + ((2 * p2) ^ ((sj & 7) << 3))];
        float wgt = wnL[jl + sj];
        v0[cc] = fmaf((float)(wq & 0xFFFFu), -INVQ, -wgt);
        v1[cc] = fmaf((float)(wq >> 16), -INVQ, -wgt);
      }
      float mx0 = v0[0], mx1 = v1[0];
#pragma unroll
      for (int cc = 1; cc < 8; ++cc) { mx0 = fmaxf(mx0, v0[cc]); mx1 = fmaxf(mx1, v1[cc]); }
      float a0 = 0.f, a1 = 0.f;
#pragma unroll
      for (int cc = 0; cc < 8; ++cc) { a0 += exp2f(v0[cc] - mx0); a1 += exp2f(v1[cc] - mx1); }
      lse_comb(mB0, sB0, mx0, a0);
      lse_comb(mB1, sB1, mx1, a1);
      __syncthreads();
    }
  }
  for (int i = tid; i < 64 * 12; i += 256) { (&Cm[0][0])[i] = -3.0e38f; (&Cs[0][0])[i] = 0.f; }
  __syncthreads();
  Cm[rn][tid & 3] = mA; Cs[rn][tid & 3] = sA;
  Cm[2 * p2][4 + g8] = mB0; Cs[2 * p2][4 + g8] = sB0;
  Cm[2 * p2 + 1][4 + g8] = mB1; Cs[2 * p2 + 1][4 + g8] = sB1;
  __syncthreads();
  if (tid < 64) {
    float m = Cm[tid][0], s = Cs[tid][0];
#pragma unroll
    for (int b = 1; b < 12; ++b) lse_comb(m, s, Cm[tid][b], Cs[tid][b]);
    Pm[(size_t)q8 * 8192 + I * 64 + tid] = m;
    Ps[(size_t)q8 * 8192 + I * 64 + tid] = s;
  }
}

// ---------- col pass: neg chunks (0..1023) + pos-col blocks (1024..1535) ----------
// rv combined in-block from Pm/Ps slots 0..7 (same order as comb_rv -> bit-identical)
__global__ __launch_bounds__(256) void colpass_k(
    const u16* __restrict__ DqPos, const u16* __restrict__ DqTri,
    float* __restrict__ Pm, float* __restrict__ Ps) {
  const int bid = blockIdx.x, tid = threadIdx.x;
  __shared__ __align__(16) u16 stg[4096];
  __shared__ float Cm[64][12], Cs[64][12];
  __shared__ float rvL[1024];
  if (bid < 1024) {
    const int q8 = bid & 7, I = bid >> 3;
    for (int t = tid; t < 1024; t += 256) {
      int j = q8 * 1024 + t;
      float m = Pm[j], s = Ps[j];
      for (int b = 1; b < 8; ++b)
        lse_comb(m, s, Pm[(size_t)b * 8192 + j], Ps[(size_t)b * 8192 + j]);
      rvL[t] = m + log2f(s);
    }
    __syncthreads();
    const int rn = tid >> 2, cn = (tid & 3) * 16;
    const int p2 = tid & 31, g8 = tid >> 5;
    const int sw = (rn & 7) << 3;
    float mA = -3.0e38f, sA = 0.f;
    float mB0 = -3.0e38f, sB0 = 0.f, mB1 = -3.0e38f, sB1 = 0.f;
    for (int Jb = q8 * 16; Jb < q8 * 16 + 16; ++Jb) {
      const int jl = (Jb - q8 * 16) * 64;
      if (Jb <= I) {
        const u16* blk = DqTri + triblk(I, Jb);
        u16x8 qa = *(const u16x8*)&blk[rn * 64 + cn];
        u16x8 qb = *(const u16x8*)&blk[rn * 64 + cn + 8];
        lse16(qa, qb, rvL + jl + cn, mA, sA);
      } else {
        const u16* blk = DqTri + triblk(Jb, I);
        u16x8 qa = *(const u16x8*)&blk[rn * 64 + cn];
        u16x8 qb = *(const u16x8*)&blk[rn * 64 + cn + 8];
        *(u16x8*)&stg[rn * 64 + (cn ^ sw)] = qa;
        *(u16x8*)&stg[rn * 64 + ((cn + 8) ^ sw)] = qb;
        __syncthreads();
        float v0[8], v1[8];
#pragma unroll
        for (int cc = 0; cc < 8; ++cc) {
          int sj = cc * 8 + g8;
          unsigned wq = *(const unsigned*)&stg[sj * 64 + ((2 * p2) ^ ((sj & 7) << 3))];
          float wgt = rvL[jl + sj];
          v0[cc] = fmaf((float)(wq & 0xFFFFu), -INVQ, -wgt);
          v1[cc] = fmaf((float)(wq >> 16), -INVQ, -wgt);
        }
        float mx0 = v0[0], mx1 = v1[0];
#pragma unroll
        for (int cc = 1; cc < 8; ++cc) { mx0 = fmaxf(mx0, v0[cc]); mx1 = fmaxf(mx1, v1[cc]); }
        float a0 = 0.f, a1 = 0.f;
#pragma unroll
        for (int cc = 0; cc < 8; ++cc) { a0 += exp2f(v0[cc] - mx0); a1 += exp2f(v1[cc] - mx1); }
        lse_comb(mB0, sB0, mx0, a0);
        lse_comb(mB1, sB1, mx1, a1);
        __syncthreads();
      }
    }
    for (int i = tid; i < 64 * 12; i += 256) { (&Cm[0][0])[i] = -3.0e38f; (&Cs[0][0])[i] = 0.f; }
    __syncthreads();
    Cm[rn][tid & 3] = mA; Cs[rn][tid & 3] = sA;
    Cm[2 * p2][4 + g8] = mB0; Cs[2 * p2][4 + g8] = sB0;
    Cm[2 * p2 + 1][4 + g8] = mB1; Cs[2 * p2 + 1][4 + g8] = sB1;
    __syncthreads();
    if (tid < 64) {
      float m = Cm[tid][0], s = Cs[tid][0];
#pragma unroll
      for (int b2 = 1; b2 < 12; ++b2) lse_comb(m, s, Cm[tid][b2], Cs[tid][b2]);
      Pm[(size_t)(72 + q8) * 8192 + I * 64 + tid] = m;
      Ps[(size_t)(72 + q8) * 8192 + I * 64 + tid] = s;
    }
  } else {
    const int b2 = bid - 1024;
    const int jb = b2 & 7, ic = b2 >> 3;
    int j0 = jb * 1024 + tid * 4;
    int i0 = ic * 128;
    if (tid < 128) {
      int j = i0 + tid;
      float m = Pm[j], s = Ps[j];
      for (int b = 1; b < 8; ++b)
        lse_comb(m, s, Pm[(size_t)b * 8192 + j], Ps[(size_t)b * 8192 + j]);
      rvL[tid] = m + log2f(s);
    }
    __syncthreads();
    float m[4], s[4];
#pragma unroll
    for (int e = 0; e < 4; ++e) { m[e] = -3.0e38f; s[e] = 0.f; }
    for (int ib = 0; ib < 16; ++ib) {
      float v[4][8];
#pragma unroll
      for (int ii = 0; ii < 8; ++ii) {
        int i = i0 + ib * 8 + ii;
        u16x4 qv = *(const u16x4*)&DqPos[(size_t)i * 8192 + j0];
        float ri = rvL[ib * 8 + ii];
#pragma unroll
        for (int e = 0; e < 4; ++e) v[e][ii] = fmaf((float)qv[e], -INVQ, -ri);
      }
#pragma unroll
      for (int e = 0; e < 4; ++e) {
        float mx = v[e][0];
#pragma unroll
        for (int ii = 1; ii < 8; ++ii) mx = fmaxf(mx, v[e][ii]);
        float ac = 0.f;
#pragma unroll
        for (int ii = 0; ii < 8; ++ii) ac += exp2f(v[e][ii] - mx);
        lse_comb(m[e], s[e], mx, ac);
      }
    }
#pragma unroll
    for (int e = 0; e < 4; ++e) {
      Pm[(size_t)(8 + ic) * 8192 + j0 + e] = m[e];
      Ps[(size_t)(8 + ic) * 8192 + j0 + e] = s[e];
    }
  }
}

// rv = LSE over row slots 0..7 (final materialization for pv)
__global__ void comb_rv_k(const float* __restrict__ Pm, const float* __restrict__ Ps,
                          float* __restrict__ rv) {
  int j = blockIdx.x * 256 + threadIdx.x;
  float m = Pm[j], s = Ps[j];
  for (int b = 1; b < 8; ++b)
    lse_comb(m, s, Pm[(size_t)b * 8192 + j], Ps[(size_t)b * 8192 + j]);
  rv[j] = m + log2f(s);
}

// cpos from slots 8..71; cneg from slots 72..79 (final materialization for pv)
__global__ void comb_cpc_k(const float* __restrict__ Pm, const float* __restrict__ Ps,
                           float* __restrict__ cpos, float* __restrict__ cneg) {
  int j = blockIdx.x * 256 + threadIdx.x;
  if (j < 8192) {
    float m = Pm[(size_t)8 * 8192 + j], s = Ps[(size_t)8 * 8192 + j];
    for (int b = 9; b < 72; ++b)
      lse_comb(m, s, Pm[(size_t)b * 8192 + j], Ps[(size_t)b * 8192 + j]);
    cpos[j] = m + log2f(s);
  } else {
    int jj = j - 8192;
    float m = Pm[(size_t)72 * 8192 + jj], s = Ps[(size_t)72 * 8192 + jj];
    for (int b = 73; b < 80; ++b)
      lse_comb(m, s, Pm[(size_t)b * 8192 + jj], Ps[(size_t)b * 8192 + jj]);
    cneg[jj] = m + log2f(s);
  }
}

// ---------- PV: Mpart[kh] = A_half[:, kh] @ B^T, plus partial rowsum(A) ----------
template <bool NEG>
__global__ __launch_bounds__(512) void pv_k(
    const u16* __restrict__ DqPos, const u16* __restrict__ DqTri,
    const float* __restrict__ rvec, const float* __restrict__ w,
    const u16* __restrict__ BT, float* __restrict__ Mout,
    float* __restrict__ sout) {
  const int tid = threadIdx.x, lane = tid & 63, wave = tid >> 6;
  const int I = blockIdx.y;   // 64-row stripe
  const int kh = blockIdx.x;  // K half: j in [kh*4096, +4096)
  __shared__ __align__(16) u16 AT[64 * 128];
  __shared__ __align__(16) u16 Bs[4 * 256 * 32];
  __shared__ __align__(16) u16 stg[NEG ? 2 * 4096 : 8];
  __shared__ float rvS[64];
  __shared__ float SredN[64][8];
  __shared__ float SredT[64][8];
  const int wrg = (wave >> 2) * 32, wcg = (wave & 3) * 64;
  const int fr = lane & 15, ko = (lane >> 4) * 8;
  const int rn = tid >> 3;          // 0..63 (natural A-build row)
  const int cnp = (tid & 7) * 16;   // pos: 16 cols/thread
  const int cnn = (tid & 7) * 8;    // neg natural/stage: 8 cols/thread
  const int swr = (rn & 7) << 3;
  const int p = tid & 63, sjg = tid >> 6;  // transposed read org
  const int swp = (p & 7) << 3;
  float asumN = 0.f, asumT = 0.f;
  if (tid < 64) rvS[tid] = rvec[I * 64 + tid];
  __syncthreads();
  const float riN = rvS[rn];
  const float riT = rvS[p];
  f32x4 acc[2][4] = {};

  for (int jc = 0; jc < 32; ++jc) {
    const int j0 = (kh * 32 + jc) * 128;
    __syncthreads();  // guard AT/Bs/stg overwrite vs previous MFMA/stg reads
#pragma unroll
    for (int ks = 0; ks < 4; ++ks) {
      int brow = wave * 32 + (lane >> 2);
      int bcol = (lane & 3) * 8;
      gload16(BT + (size_t)brow * 8192 + j0 + ks * 32 + bcol,
              Bs + ks * 8192 + wave * 32 * 32);
      gload16(BT + (size_t)(brow + 16) * 8192 + j0 + ks * 32 + bcol,
              Bs + ks * 8192 + (wave * 32 + 16) * 32);
    }
    if constexpr (!NEG) {
      const u16* rp = DqPos + (size_t)(I * 64 + rn) * 8192 + j0 + cnp;
      u16x8 qa = *(const u16x8*)rp;
      u16x8 qb = *(const u16x8*)(rp + 8);
      const float* wp = w + j0 + cnp;
      f32x4 w0 = *(const f32x4*)wp;
      f32x4 w1 = *(const f32x4*)(wp + 4);
      f32x4 w2 = *(const f32x4*)(wp + 8);
      f32x4 w3 = *(const f32x4*)(wp + 12);
      union { u16x8 v; u16 e[8]; } pk0, pk1;
#pragma unroll
      for (int e = 0; e < 4; ++e) {
        float a0 = exp2f(fmaf((float)qa[e], -INVQ, -riN - w0[e]));
        float a1 = exp2f(fmaf((float)qa[4 + e], -INVQ, -riN - w1[e]));
        float a2 = exp2f(fmaf((float)qb[e], -INVQ, -riN - w2[e]));
        float a3 = exp2f(fmaf((float)qb[4 + e], -INVQ, -riN - w3[e]));
        asumN += a0 + a1 + a2 + a3;
        pk0.e[e] = f2bf(a0); pk0.e[4 + e] = f2bf(a1);
        pk1.e[e] = f2bf(a2); pk1.e[4 + e] = f2bf(a3);
      }
      *(u16x8*)&AT[rn * 128 + (cnp ^ swr)] = pk0.v;
      *(u16x8*)&AT[rn * 128 + ((cnp + 8) ^ swr)] = pk1.v;
    } else {
      bool anytr = false;
#pragma unroll
      for (int h = 0; h < 2; ++h) {
        const int Jb = kh * 64 + jc * 2 + h;
        if (Jb <= I) {
          const u16* blk = DqTri + triblk(I, Jb);
          u16x8 q = *(const u16x8*)&blk[rn * 64 + cnn];
          const float* wp = w + Jb * 64 + cnn;
          f32x4 w0 = *(const f32x4*)wp;
          f32x4 w1 = *(const f32x4*)(wp + 4);
          union { u16x8 v; u16 e[8]; } pk;
#pragma unroll
          for (int e = 0; e < 4; ++e) {
            float a0 = exp2f(fmaf((float)q[e], -INVQ, -riN - w0[e]));
            float a1 = exp2f(fmaf((float)q[4 + e], -INVQ, -riN - w1[e]));
            asumN += a0 + a1;
            pk.e[e] = f2bf(a0); pk.e[4 + e] = f2bf(a1);
          }
          *(u16x8*)&AT[rn * 128 + ((h * 64 + cnn) ^ swr)] = pk.v;
        } else {
          anytr = true;
          const u16* blk = DqTri + triblk(Jb, I);
          u16x8 q = *(const u16x8*)&blk[rn * 64 + cnn];
          *(u16x8*)&stg[h * 4096 + rn * 64 + (cnn ^ swr)] = q;
        }
      }
      if (anytr) {
        __syncthreads();
#pragma unroll
        for (int h = 0; h < 2; ++h) {
          const int Jb = kh * 64 + jc * 2 + h;
          if (Jb <= I) continue;
#pragma unroll
          for (int cc = 0; cc < 8; ++cc) {
            int sj = cc * 8 + sjg;
            u16 q = stg[h * 4096 + sj * 64 + (p ^ ((sj & 7) << 3))];
            float a = exp2f(fmaf((float)q, -INVQ, -riT - w[Jb * 64 + sj]));
            asumT += a;
            AT[p * 128 + ((h * 64 + sj) ^ swp)] = f2bf(a);
          }
        }
      }
    }
    __syncthreads();  // AT + Bs (gload drained) ready
#pragma unroll
    for (int ks = 0; ks < 4; ++ks) {
      bf16x8 a2[2], b2[4];
#pragma unroll
      for (int m = 0; m < 2; ++m) {
        int rl = wrg + m * 16 + fr;
        a2[m] = *(const bf16x8*)&AT[rl * 128 + ((ks * 32 + ko) ^ ((rl & 7) << 3))];
      }
#pragma unroll
      for (int n = 0; n < 4; ++n)
        b2[n] = *(const bf16x8*)&Bs[ks * 8192 + (wcg + n * 16 + fr) * 32 + ko];
#pragma unroll
      for (int m = 0; m < 2; ++m)
#pragma unroll
        for (int n = 0; n < 4; ++n)
          acc[m][n] = __builtin_amdgcn_mfma_f32_16x16x32_bf16(a2[m], b2[n], acc[m][n], 0, 0, 0);
    }
  }
  // write M partial
#pragma unroll
  for (int m = 0; m < 2; ++m)
#pragma unroll
    for (int n = 0; n < 4; ++n)
#pragma unroll
      for (int q = 0; q < 4; ++q) {
        int row = I * 64 + wrg + m * 16 + (lane >> 4) * 4 + q;
        int d = wcg + n * 16 + fr;
        Mout[(size_t)kh * 2097152 + (size_t)row * 256 + d] = acc[m][n][q];
      }
  // partial rowsum(A)
  SredN[rn][tid & 7] = asumN;
  SredT[p][sjg] = NEG ? asumT : 0.f;
  __syncthreads();
  if (tid < 64) {
    float s = 0.f;
#pragma unroll
    for (int b = 0; b < 8; ++b) s += SredN[tid][b] + SredT[tid][b];
    sout[kh * 8192 + I * 64 + tid] = s;
  }
}

// ---------- elementwise / transpose / norms ----------
__global__ void convert_split_k(const float* __restrict__ src, u16* __restrict__ hi,
                                u16* __restrict__ lo, int n) {
  int i = blockIdx.x * 256 + threadIdx.x;
  if (i < n) {
    float v = src[i];
    u16 h = f2bf(v);
    hi[i] = h;
    lo[i] = f2bf(v - bf2f(h));
  }
}

__global__ void transpose_split_k(const float* __restrict__ src, int K, int N,
                                  u16* __restrict__ hi, u16* __restrict__ lo) {
  __shared__ float t[32][33];
  int x = threadIdx.x & 31, y = threadIdx.x >> 5;
  int k0 = blockIdx.x * 32, n0 = blockIdx.y * 32;
  for (int yy = y; yy < 32; yy += 8) t[yy][x] = src[(size_t)(k0 + yy) * N + n0 + x];
  __syncthreads();
  for (int yy = y; yy < 32; yy += 8) {
    float v = t[x][yy];
    size_t idx = (size_t)(n0 + yy) * K + k0 + x;
    u16 h = f2bf(v);
    hi[idx] = h;
    lo[idx] = f2bf(v - bf2f(h));
  }
}

__global__ void transpose_b16_k(const float* __restrict__ src, int M, int D,
                                u16* __restrict__ dst) {
  __shared__ float t[32][33];
  int x = threadIdx.x & 31, y = threadIdx.x >> 5;
  int m0 = blockIdx.x * 32, d0 = blockIdx.y * 32;
  for (int yy = y; yy < 32; yy += 8) t[yy][x] = src[(size_t)(m0 + yy) * D + d0 + x];
  __syncthreads();
  for (int yy = y; yy < 32; yy += 8)
    dst[(size_t)(d0 + yy) * M + m0 + x] = f2bf(t[x][yy]);
}

__global__ void rownorm_k(const float* __restrict__ src, float* __restrict__ o) {
  int i = blockIdx.x, t = threadIdx.x;
  float s = 0.f;
  for (int d = t; d < 256; d += 64) {
    float v = src[(size_t)i * 256 + d];
    s += v * v;
  }
  for (int off = 32; off; off >>= 1) s += __shfl_down(s, off, 64);
  if (t == 0) o[i] = s;
}

__global__ void zero_k(float* __restrict__ p, int n) {
  int i = blockIdx.x * 256 + threadIdx.x;
  if (i < n) p[i] = 0.f;
}

__global__ void decode_k(float* __restrict__ out, float x, int n) {
  int i = blockIdx.x * 256 + threadIdx.x;
  if (i < n) out[i] = x;
}

__global__ void final_out_k(const float* __restrict__ M1, const float* __restrict__ M2,
                            const float* __restrict__ sp, const float* __restrict__ sn,
                            float* __restrict__ out) {
  __shared__ float S[256];
  int i = blockIdx.x, d = threadIdx.x;
  size_t idx = (size_t)i * 256 + d;
  float spv = sp[i] + sp[8192 + i];
  float snv = sn[i] + sn[8192 + i];
  float v = snv * (M1[idx] + M1[2097152 + idx]) - spv * (M2[idx] + M2[2097152 + idx]);
  S[d] = v * v;
  __syncthreads();
  for (int off = 128; off; off >>= 1) {
    if (d < off) S[d] += S[d + off];
    __syncthreads();
  }
  if (d == 0) out[i] = S[0];
}

// ---------- host ----------
extern "C" void kernel_launch(void* const* d_in, const int* in_sizes, int n_in,
                              void* d_out, int out_size, void* d_ws, size_t ws_size,
                              hipStream_t stream) {
  (void)in_sizes; (void)n_in; (void)out_size;
  const float* pos = (const float*)d_in[0];
  const float* z   = (const float*)d_in[1];
  const float* W1  = (const float*)d_in[2];
  const float* b1  = (const float*)d_in[3];
  const float* W2  = (const float*)d_in[4];
  const float* b2  = (const float*)d_in[5];
  const float* W3  = (const float*)d_in[6];
  const float* b3  = (const float*)d_in[7];
  const float* W4  = (const float*)d_in[8];
  const float* b4  = (const float*)d_in[9];
  const float* W5  = (const float*)d_in[10];
  const float* b5  = (const float*)d_in[11];
  float* out = (float*)d_out;

  if (ws_size < (size_t)261500000) {
    decode_k<<<32, 256, 0, stream>>>(out, (float)(double)(ws_size >> 10), 8192);
    return;
  }

  char* wsp = (char*)d_ws;
  size_t off = 0;
  auto alloc = [&](size_t bytes) -> char* {
    char* p = wsp + off;
    off += (bytes + 255) & ~(size_t)255;
    return p;
  };
  u16* DqPos = (u16*)alloc((size_t)8192 * 8192 * 2);  // 134.2 MB
  u16* DqTri = (u16*)alloc((size_t)8256 * 4096 * 2);  // 67.6 MB (lower block-triangle)
  u16* Yh    = (u16*)alloc((size_t)16384 * 256 * 2);  // pos rows [0:8192), gen [8192:)
  u16* Yl    = (u16*)alloc((size_t)16384 * 256 * 2);
  u16* posT  = (u16*)alloc((size_t)256 * 8192 * 2);
  u16* genT  = (u16*)alloc((size_t)256 * 8192 * 2);
  float* yN2 = (float*)alloc(16384 * 4);
  float* rv  = (float*)alloc(8192 * 4);
  float* cpos = (float*)alloc(8192 * 4);
  float* cneg = (float*)alloc(8192 * 4);
  float* spv = (float*)alloc(2 * 8192 * 4);
  float* snv = (float*)alloc(2 * 8192 * 4);
  float* M1  = (float*)alloc((size_t)2 * 8192 * 256 * 4);  // K-split partials (16.8 MB)
  float* M2  = (float*)alloc((size_t)2 * 8192 * 256 * 4);
  // Pm/Ps (PSLOTS x 8192 f32 = 2.62 MB each) alias M1: dead before pv_k writes M1
  float* Pm = M1;
  float* Ps = Pm + (size_t)PSLOTS * 8192;

  // transient MLP arena aliases DqPos (~94 MB < 134 MB; dead before DqPos written)
  size_t toff = 0;
  char* tbase = (char*)DqPos;
  auto talloc = [&](size_t bytes) -> char* {
    char* p = tbase + toff;
    toff += (bytes + 255) & ~(size_t)255;
    return p;
  };
  u16* zh    = (u16*)talloc((size_t)8192 * 128 * 2);
  u16* zl    = (u16*)talloc((size_t)8192 * 128 * 2);
  u16* W1Th  = (u16*)talloc(1024 * 128 * 2);
  u16* W1Tl  = (u16*)talloc(1024 * 128 * 2);
  u16* W2Th  = (u16*)talloc(1024 * 1024 * 2);
  u16* W2Tl  = (u16*)talloc(1024 * 1024 * 2);
  u16* W3Th  = (u16*)talloc(1024 * 1024 * 2);
  u16* W3Tl  = (u16*)talloc(1024 * 1024 * 2);
  u16* W4Th  = (u16*)talloc(1024 * 1024 * 2);
  u16* W4Tl  = (u16*)talloc(1024 * 1024 * 2);
  u16* W5Th  = (u16*)talloc(256 * 1024 * 2);
  u16* W5Tl  = (u16*)talloc(256 * 1024 * 2);
  u16* h1h   = (u16*)talloc((size_t)8192 * 1024 * 2);
  u16* h1l   = (u16*)talloc((size_t)8192 * 1024 * 2);
  u16* h2h   = (u16*)talloc((size_t)8192 * 1024 * 2);
  u16* h2l   = (u16*)talloc((size_t)8192 * 1024 * 2);
  float* genf = (float*)talloc((size_t)8192 * 256 * 4);

  u16* genH = Yh + (size_t)8192 * 256;
  u16* genL = Yl + (size_t)8192 * 256;
  float* pN2 = yN2;
  float* gN2 = yN2 + 8192;

  // ---- preprocessing ----
  convert_split_k<<<4096, 256, 0, stream>>>(z, zh, zl, 8192 * 128);
  convert_split_k<<<8192, 256, 0, stream>>>(pos, Yh, Yl, 8192 * 256);
  transpose_split_k<<<dim3(4, 32), 256, 0, stream>>>(W1, 128, 1024, W1Th, W1Tl);
  transpose_split_k<<<dim3(32, 32), 256, 0, stream>>>(W2, 1024, 1024, W2Th, W2Tl);
  transpose_split_k<<<dim3(32, 32), 256, 0, stream>>>(W3, 1024, 1024, W3Th, W3Tl);
  transpose_split_k<<<dim3(32, 32), 256, 0, stream>>>(W4, 1024, 1024, W4Th, W4Tl);
  transpose_split_k<<<dim3(32, 8), 256, 0, stream>>>(W5, 1024, 256, W5Th, W5Tl);
  rownorm_k<<<8192, 64, 0, stream>>>(pos, pN2);
  transpose_b16_k<<<dim3(256, 8), 256, 0, stream>>>(pos, 8192, 256, posT);

  // ---- MLP (split-bf16, fused bias+selu; 64x128 tiles for occupancy) ----
  gemm_k<64, 128, 2, 2, EPI_MLP><<<dim3(8, 128), 256, 0, stream>>>(
      zh, zl, 128, W1Th, W1Tl, 128, 128, nullptr, 0, b1, 1, h1h, h1l, 1024,
      nullptr, nullptr, nullptr);
  gemm_k<64, 128, 2, 2, EPI_MLP><<<dim3(8, 128), 256, 0, stream>>>(
      h1h, h1l, 1024, W2Th, W2Tl, 1024, 1024, nullptr, 0, b2, 1, h2h, h2l, 1024,
      nullptr, nullptr, nullptr);
  gemm_k<64, 128, 2, 2, EPI_MLP><<<dim3(8, 128), 256, 0, stream>>>(
      h2h, h2l, 1024, W3Th, W3Tl, 1024, 1024, nullptr, 0, b3, 1, h1h, h1l, 1024,
      nullptr, nullptr, nullptr);
  gemm_k<64, 128, 2, 2, EPI_MLP><<<dim3(8, 128), 256, 0, stream>>>(
      h1h, h1l, 1024, W4Th, W4Tl, 1024, 1024, nullptr, 0, b4, 1, h2h, h2l, 1024,
      nullptr, nullptr, nullptr);
  gemm_k<64, 128, 2, 2, EPI_MLP><<<dim3(2, 128), 256, 0, stream>>>(
      h2h, h2l, 1024, W5Th, W5Tl, 1024, 1024, genf, 256, b5, 0,
      genH, genL, 256, nullptr, nullptr, nullptr);

  rownorm_k<<<8192, 64, 0, stream>>>(genf, gN2);
  transpose_b16_k<<<dim3(256, 8), 256, 0, stream>>>(genf, 8192, 256, genT);

  // ---- build stored distance matrices (un-fused; transients dead) ----
  gemm_k<128, 128, 2, 2, EPI_DISTQ><<<4096, 256, 0, stream>>>(
      genH, genL, 256, Yh, Yl, 256, 256, nullptr, 0, nullptr, 0, nullptr,
      nullptr, 0, gN2, pN2, DqPos);
  gemm_k<128, 128, 2, 2, EPI_NEGTRI><<<2080, 256, 0, stream>>>(
      genH, genL, 256, genH, genL, 256, 256, nullptr, 0, nullptr, 0, nullptr,
      nullptr, 0, gN2, gN2, DqTri);

  // ---- Sinkhorn (log2 domain): 5 x {row, col}; combs inlined into passes ----
  zero_k<<<64, 256, 0, stream>>>(cpos, 16384);  // cpos + cneg (contiguous)
  for (int it = 0; it < 5; ++it) {
    sink_k<<<dim3(8, 128), 256, 0, stream>>>(DqPos, DqTri, cpos, cneg, Pm, Ps, it);
    colpass_k<<<1536, 256, 0, stream>>>(DqPos, DqTri, Pm, Ps);
  }
  comb_rv_k<<<32, 256, 0, stream>>>(Pm, Ps, rv);
  comb_cpc_k<<<64, 256, 0, stream>>>(Pm, Ps, cpos, cneg);

  // ---- PV from stored Dq (K-split x2, partial M/s) ----
  pv_k<false><<<dim3(2, 128), 512, 0, stream>>>(DqPos, DqTri, rv, cpos, posT, M1, spv);
  pv_k<true><<<dim3(2, 128), 512, 0, stream>>>(DqPos, DqTri, rv, cneg, genT, M2, snv);

  // ---- out_i = sum_d (sn_i*(M1a+M1b) - sp_i*(M2a+M2b))^2 ----
  final_out_k<<<8192, 256, 0, stream>>>(M1, M2, spv, snv, out);
}

// Round 14
// 1442.527 us; speedup vs baseline: 1.0790x; 1.0790x over previous
//
#include <hip/hip_runtime.h>

#define DEVI __device__ __forceinline__

typedef short bf16x8 __attribute__((ext_vector_type(8)));
typedef float f32x4 __attribute__((ext_vector_type(4)));
typedef unsigned short u16;
typedef unsigned short u16x8 __attribute__((ext_vector_type(8)));
typedef unsigned short u16x4 __attribute__((ext_vector_type(4)));

enum { EPI_MLP = 0, EPI_DISTQ = 1, EPI_NEGTRI = 2 };

#define KLOG2E_T 28.853900817779268f /* log2(e)/TEMP */
#define QSCALE 1846.6496523378733f   /* KLOG2E_T * 64 */
#define INVQ 0.015625f               /* 1/64 */
#define PSLOTS 96                    /* 0..15 row, 16..79 pos-col, 80..95 neg-col */

// ---------- small helpers ----------
DEVI u16 f2bf(float f) {
  unsigned u = __float_as_uint(f);
  return (u16)((u + 0x7FFFu + ((u >> 16) & 1u)) >> 16);
}
DEVI float bf2f(u16 h) { return __uint_as_float(((unsigned)h) << 16); }
DEVI float seluf(float x) {
  return x > 0.f ? 1.0507009873554805f * x : 1.7580993408473766f * expm1f(x);
}
DEVI void gload16(const void* g, void* l) {
  __builtin_amdgcn_global_load_lds(
      (const __attribute__((address_space(1))) unsigned*)g,
      (__attribute__((address_space(3))) unsigned*)l, 16, 0, 0);
}
DEVI void lse_comb(float& m, float& s, float m2, float s2) {
  float M = fmaxf(m, m2);
  s = s * exp2f(m - M) + s2 * exp2f(m2 - M);
  m = M;
}
DEVI size_t triblk(int I, int J) { return ((size_t)I * (I + 1) / 2 + J) * 4096; }

// ---------- GEMM: C = A * B^T, split-bf16 (hi+lo, 3 MFMA); hoisted-pointer staging ----------
template <int BM, int BN, int WM, int WN, int EPI>
__global__ __launch_bounds__(WM* WN * 64) void gemm_k(
    const u16* __restrict__ Ahi, const u16* __restrict__ Alo, int lda,
    const u16* __restrict__ Bhi, const u16* __restrict__ Blo, int ldb, int K,
    float* __restrict__ Cf, int ldc,
    const float* __restrict__ bias, int act, u16* __restrict__ Ohi,
    u16* __restrict__ Olo, int ldo,
    const float* __restrict__ xN2, const float* __restrict__ yN2,
    u16* __restrict__ Cq) {
  constexpr int NW = WM * WN;
  constexpr int FM = BM / (WM * 16), FN = BN / (WN * 16);
  constexpr int IA = BM / (16 * NW), IB = BN / (16 * NW);
  const int tid = threadIdx.x, lane = tid & 63, wave = tid >> 6;
  int bm0, bn0;
  if constexpr (EPI == EPI_DISTQ) {
    // L2 super-tile swizzle: XCD (bid&7) walks 8x8-block super-tiles (~2MB set -> L2-fit)
    int bid = (int)blockIdx.x;
    int xcd = bid & 7, p = bid >> 3;
    int st = (p >> 6) * 8 + xcd;
    int r8 = (p >> 3) & 7, c8 = p & 7;
    bm0 = ((st >> 3) * 8 + r8) * 128;
    bn0 = ((st & 7) * 8 + c8) * 128;
  } else if constexpr (EPI == EPI_NEGTRI) {
    // compact lower block-triangle: 2080 tiles of 128^2
    int t = (int)blockIdx.x;
    int a = (int)((sqrtf(8.f * (float)t + 1.f) - 1.f) * 0.5f);
    while ((a + 1) * (a + 2) / 2 <= t) ++a;
    while (a * (a + 1) / 2 > t) --a;
    int b = t - a * (a + 1) / 2;
    bm0 = a * 128;
    bn0 = b * 128;
  } else {
    bm0 = blockIdx.y * BM;
    bn0 = blockIdx.x * BN;
  }
  const int wr = (wave / WN) * (FM * 16), wc = (wave % WN) * (FN * 16);
  __shared__ __align__(16) u16 AsH[BM * 32];
  __shared__ __align__(16) u16 BsH[BN * 32];
  __shared__ __align__(16) u16 AsL[BM * 32];
  __shared__ __align__(16) u16 BsL[BN * 32];
  // hoisted staging pointers: stepped +32 per k-iter
  const int srow = lane >> 2, scol = (lane & 3) * 8;
  const u16 *pAh[IA], *pAl[IA], *pBh[IB], *pBl[IB];
  int lA[IA], lB[IB];
#pragma unroll
  for (int t = 0; t < IA; ++t) {
    int r = (wave * IA + t) * 16;
    pAh[t] = Ahi + (size_t)(bm0 + r + srow) * lda + scol;
    pAl[t] = Alo + (size_t)(bm0 + r + srow) * lda + scol;
    lA[t] = r * 32;
  }
#pragma unroll
  for (int t = 0; t < IB; ++t) {
    int r = (wave * IB + t) * 16;
    pBh[t] = Bhi + (size_t)(bn0 + r + srow) * ldb + scol;
    pBl[t] = Blo + (size_t)(bn0 + r + srow) * ldb + scol;
    lB[t] = r * 32;
  }
  f32x4 acc[FM][FN] = {};
  const int fr = lane & 15, ko = (lane >> 4) * 8;
  for (int k0 = 0; k0 < K; k0 += 32) {
#pragma unroll
    for (int t = 0; t < IA; ++t) {
      gload16(pAh[t], AsH + lA[t]); pAh[t] += 32;
      gload16(pAl[t], AsL + lA[t]); pAl[t] += 32;
    }
#pragma unroll
    for (int t = 0; t < IB; ++t) {
      gload16(pBh[t], BsH + lB[t]); pBh[t] += 32;
      gload16(pBl[t], BsL + lB[t]); pBl[t] += 32;
    }
    __syncthreads();
    bf16x8 ah[FM], bh[FN], al[FM], bl[FN];
#pragma unroll
    for (int m = 0; m < FM; ++m) ah[m] = *(const bf16x8*)&AsH[(wr + m * 16 + fr) * 32 + ko];
#pragma unroll
    for (int n = 0; n < FN; ++n) bh[n] = *(const bf16x8*)&BsH[(wc + n * 16 + fr) * 32 + ko];
#pragma unroll
    for (int m = 0; m < FM; ++m) al[m] = *(const bf16x8*)&AsL[(wr + m * 16 + fr) * 32 + ko];
#pragma unroll
    for (int n = 0; n < FN; ++n) bl[n] = *(const bf16x8*)&BsL[(wc + n * 16 + fr) * 32 + ko];
#pragma unroll
    for (int m = 0; m < FM; ++m)
#pragma unroll
      for (int n = 0; n < FN; ++n) {
        acc[m][n] = __builtin_amdgcn_mfma_f32_16x16x32_bf16(ah[m], bh[n], acc[m][n], 0, 0, 0);
        acc[m][n] = __builtin_amdgcn_mfma_f32_16x16x32_bf16(al[m], bh[n], acc[m][n], 0, 0, 0);
        acc[m][n] = __builtin_amdgcn_mfma_f32_16x16x32_bf16(ah[m], bl[n], acc[m][n], 0, 0, 0);
      }
    __syncthreads();
  }
#pragma unroll
  for (int m = 0; m < FM; ++m)
#pragma unroll
    for (int n = 0; n < FN; ++n)
#pragma unroll
      for (int q = 0; q < 4; ++q) {
        int row = bm0 + wr + m * 16 + (lane >> 4) * 4 + q;
        int col = bn0 + wc + n * 16 + fr;
        float v = acc[m][n][q];
        if constexpr (EPI == EPI_MLP) {
          v += bias[col];
          if (act) v = seluf(v);
          u16 h = f2bf(v);
          size_t idx = (size_t)row * ldo + col;
          Ohi[idx] = h;
          Olo[idx] = f2bf(v - bf2f(h));
          if (Cf) Cf[(size_t)row * ldc + col] = v;
        } else if constexpr (EPI == EPI_DISTQ) {
          float d2 = fmaxf(xN2[row] + yN2[col] - 2.f * v, 0.f);
          float qf = fminf(QSCALE * sqrtf(d2), 65535.f);
          Cq[(size_t)row * 8192 + col] = (u16)__float2uint_rn(qf);
        } else {  // EPI_NEGTRI
          int bI = row >> 6, bJ = col >> 6;
          if (bJ <= bI) {
            float d2 = fmaxf(xN2[row] + yN2[col] - 2.f * v, 0.f);
            float qf = fminf(QSCALE * sqrtf(d2), 65535.f);
            u16 qu = (u16)__float2uint_rn(qf);
            if (row == col) qu = 65535;
            Cq[triblk(bI, bJ) + (row & 63) * 64 + (col & 63)] = qu;
          }
        }
      }
}

// ---------- shared LSE micro-op ----------
DEVI void lse16(const u16x8& qa, const u16x8& qb, const float* __restrict__ w,
                float& m, float& s) {
  f32x4 w0 = *(const f32x4*)w;
  f32x4 w1 = *(const f32x4*)(w + 4);
  f32x4 w2 = *(const f32x4*)(w + 8);
  f32x4 w3 = *(const f32x4*)(w + 12);
  float v[16];
#pragma unroll
  for (int e = 0; e < 4; ++e) {
    v[e] = fmaf((float)qa[e], -INVQ, -w0[e]);
    v[4 + e] = fmaf((float)qa[4 + e], -INVQ, -w1[e]);
    v[8 + e] = fmaf((float)qb[e], -INVQ, -w2[e]);
    v[12 + e] = fmaf((float)qb[4 + e], -INVQ, -w3[e]);
  }
  float mx = v[0];
#pragma unroll
  for (int e = 1; e < 16; ++e) mx = fmaxf(mx, v[e]);
  float ac = 0.f;
#pragma unroll
  for (int e = 0; e < 16; ++e) ac += exp2f(v[e] - mx);
  lse_comb(m, s, mx, ac);
}

// ---------- Sinkhorn row-LSE: stripe of 64 rows, SIXTEENTH of j-range ----------
// grid (16, 128): q16 covers 512 pos cols + 8 tri blocks. Output Pm[q16][I*64+r].
__global__ __launch_bounds__(256) void sink_k(
    const u16* __restrict__ DqPos, const u16* __restrict__ DqTri,
    const float* __restrict__ wpos, const float* __restrict__ wneg,
    float* __restrict__ Pm, float* __restrict__ Ps) {
  const int tid = threadIdx.x;
  const int I = blockIdx.y, q16 = blockIdx.x;
  __shared__ __align__(16) u16 stg[4096];
  __shared__ float Cm[64][12], Cs[64][12];
  const int rn = tid >> 2, cn = (tid & 3) * 16;  // natural org: 4 thr/row
  const int p2 = tid & 31, g8 = tid >> 5;        // transposed org
  float mA = -3.0e38f, sA = 0.f;
  float mB0 = -3.0e38f, sB0 = 0.f, mB1 = -3.0e38f, sB1 = 0.f;
  const int sw = (rn & 7) << 3;

  {
    const size_t rowbase = (size_t)(I * 64 + rn) * 8192;
    for (int jc = 0; jc < 8; ++jc) {
      int j0 = q16 * 512 + jc * 64 + cn;
      u16x8 qa = *(const u16x8*)&DqPos[rowbase + j0];
      u16x8 qb = *(const u16x8*)&DqPos[rowbase + j0 + 8];
      lse16(qa, qb, wpos + j0, mA, sA);
    }
  }
  for (int Jb = q16 * 8; Jb < q16 * 8 + 8; ++Jb) {
    if (Jb <= I) {
      const u16* blk = DqTri + triblk(I, Jb);
      u16x8 qa = *(const u16x8*)&blk[rn * 64 + cn];
      u16x8 qb = *(const u16x8*)&blk[rn * 64 + cn + 8];
      lse16(qa, qb, wneg + Jb * 64 + cn, mA, sA);
    } else {
      const u16* blk = DqTri + triblk(Jb, I);
      u16x8 qa = *(const u16x8*)&blk[rn * 64 + cn];
      u16x8 qb = *(const u16x8*)&blk[rn * 64 + cn + 8];
      *(u16x8*)&stg[rn * 64 + (cn ^ sw)] = qa;
      *(u16x8*)&stg[rn * 64 + ((cn + 8) ^ sw)] = qb;
      __syncthreads();
      float v0[8], v1[8];
#pragma unroll
      for (int cc = 0; cc < 8; ++cc) {
        int sj = cc * 8 + g8;
        unsigned wq = *(const unsigned*)&stg[sj * 64 + ((2 * p2) ^ ((sj & 7) << 3))];
        float wgt = wneg[Jb * 64 + sj];
        v0[cc] = fmaf((float)(wq & 0xFFFFu), -INVQ, -wgt);
        v1[cc] = fmaf((float)(wq >> 16), -INVQ, -wgt);
      }
      float mx0 = v0[0], mx1 = v1[0];
#pragma unroll
      for (int cc = 1; cc < 8; ++cc) { mx0 = fmaxf(mx0, v0[cc]); mx1 = fmaxf(mx1, v1[cc]); }
      float a0 = 0.f, a1 = 0.f;
#pragma unroll
      for (int cc = 0; cc < 8; ++cc) { a0 += exp2f(v0[cc] - mx0); a1 += exp2f(v1[cc] - mx1); }
      lse_comb(mB0, sB0, mx0, a0);
      lse_comb(mB1, sB1, mx1, a1);
      __syncthreads();
    }
  }
  for (int i = tid; i < 64 * 12; i += 256) { (&Cm[0][0])[i] = -3.0e38f; (&Cs[0][0])[i] = 0.f; }
  __syncthreads();
  Cm[rn][tid & 3] = mA; Cs[rn][tid & 3] = sA;
  Cm[2 * p2][4 + g8] = mB0; Cs[2 * p2][4 + g8] = sB0;
  Cm[2 * p2 + 1][4 + g8] = mB1; Cs[2 * p2 + 1][4 + g8] = sB1;
  __syncthreads();
  if (tid < 64) {
    float m = Cm[tid][0], s = Cs[tid][0];
#pragma unroll
    for (int b = 1; b < 12; ++b) lse_comb(m, s, Cm[tid][b], Cs[tid][b]);
    Pm[(size_t)q16 * 8192 + I * 64 + tid] = m;
    Ps[(size_t)q16 * 8192 + I * 64 + tid] = s;
  }
}

// ---------- col pass: neg chunks (0..2047) + pos-col blocks (2048..2559) ----------
__global__ __launch_bounds__(256) void colpass_k(
    const u16* __restrict__ DqPos, const u16* __restrict__ DqTri,
    const float* __restrict__ rv, float* __restrict__ Pm, float* __restrict__ Ps) {
  const int bid = blockIdx.x, tid = threadIdx.x;
  __shared__ __align__(16) u16 stg[4096];
  __shared__ float Cm[64][12], Cs[64][12];
  if (bid < 2048) {
    const int q16 = bid & 15, I = bid >> 4;
    const int rn = tid >> 2, cn = (tid & 3) * 16;
    const int p2 = tid & 31, g8 = tid >> 5;
    const int sw = (rn & 7) << 3;
    float mA = -3.0e38f, sA = 0.f;
    float mB0 = -3.0e38f, sB0 = 0.f, mB1 = -3.0e38f, sB1 = 0.f;
    for (int Jb = q16 * 8; Jb < q16 * 8 + 8; ++Jb) {
      if (Jb <= I) {
        const u16* blk = DqTri + triblk(I, Jb);
        u16x8 qa = *(const u16x8*)&blk[rn * 64 + cn];
        u16x8 qb = *(const u16x8*)&blk[rn * 64 + cn + 8];
        lse16(qa, qb, rv + Jb * 64 + cn, mA, sA);
      } else {
        const u16* blk = DqTri + triblk(Jb, I);
        u16x8 qa = *(const u16x8*)&blk[rn * 64 + cn];
        u16x8 qb = *(const u16x8*)&blk[rn * 64 + cn + 8];
        *(u16x8*)&stg[rn * 64 + (cn ^ sw)] = qa;
        *(u16x8*)&stg[rn * 64 + ((cn + 8) ^ sw)] = qb;
        __syncthreads();
        float v0[8], v1[8];
#pragma unroll
        for (int cc = 0; cc < 8; ++cc) {
          int sj = cc * 8 + g8;
          unsigned wq = *(const unsigned*)&stg[sj * 64 + ((2 * p2) ^ ((sj & 7) << 3))];
          float wgt = rv[Jb * 64 + sj];
          v0[cc] = fmaf((float)(wq & 0xFFFFu), -INVQ, -wgt);
          v1[cc] = fmaf((float)(wq >> 16), -INVQ, -wgt);
        }
        float mx0 = v0[0], mx1 = v1[0];
#pragma unroll
        for (int cc = 1; cc < 8; ++cc) { mx0 = fmaxf(mx0, v0[cc]); mx1 = fmaxf(mx1, v1[cc]); }
        float a0 = 0.f, a1 = 0.f;
#pragma unroll
        for (int cc = 0; cc < 8; ++cc) { a0 += exp2f(v0[cc] - mx0); a1 += exp2f(v1[cc] - mx1); }
        lse_comb(mB0, sB0, mx0, a0);
        lse_comb(mB1, sB1, mx1, a1);
        __syncthreads();
      }
    }
    for (int i = tid; i < 64 * 12; i += 256) { (&Cm[0][0])[i] = -3.0e38f; (&Cs[0][0])[i] = 0.f; }
    __syncthreads();
    Cm[rn][tid & 3] = mA; Cs[rn][tid & 3] = sA;
    Cm[2 * p2][4 + g8] = mB0; Cs[2 * p2][4 + g8] = sB0;
    Cm[2 * p2 + 1][4 + g8] = mB1; Cs[2 * p2 + 1][4 + g8] = sB1;
    __syncthreads();
    if (tid < 64) {
      float m = Cm[tid][0], s = Cs[tid][0];
#pragma unroll
      for (int b2 = 1; b2 < 12; ++b2) lse_comb(m, s, Cm[tid][b2], Cs[tid][b2]);
      Pm[(size_t)(80 + q16) * 8192 + I * 64 + tid] = m;
      Ps[(size_t)(80 + q16) * 8192 + I * 64 + tid] = s;
    }
  } else {
    const int b2 = bid - 2048;
    const int jb = b2 & 7, ic = b2 >> 3;
    int j0 = jb * 1024 + tid * 4;
    int i0 = ic * 128;
    float m[4], s[4];
#pragma unroll
    for (int e = 0; e < 4; ++e) { m[e] = -3.0e38f; s[e] = 0.f; }
    for (int ib = 0; ib < 16; ++ib) {
      float v[4][8];
#pragma unroll
      for (int ii = 0; ii < 8; ++ii) {
        int i = i0 + ib * 8 + ii;
        u16x4 qv = *(const u16x4*)&DqPos[(size_t)i * 8192 + j0];
        float ri = rv[i];
#pragma unroll
        for (int e = 0; e < 4; ++e) v[e][ii] = fmaf((float)qv[e], -INVQ, -ri);
      }
#pragma unroll
      for (int e = 0; e < 4; ++e) {
        float mx = v[e][0];
#pragma unroll
        for (int ii = 1; ii < 8; ++ii) mx = fmaxf(mx, v[e][ii]);
        float ac = 0.f;
#pragma unroll
        for (int ii = 0; ii < 8; ++ii) ac += exp2f(v[e][ii] - mx);
        lse_comb(m[e], s[e], mx, ac);
      }
    }
#pragma unroll
    for (int e = 0; e < 4; ++e) {
      Pm[(size_t)(16 + ic) * 8192 + j0 + e] = m[e];
      Ps[(size_t)(16 + ic) * 8192 + j0 + e] = s[e];
    }
  }
}

// rv = LSE over row slots 0..15
__global__ void comb_rv_k(const float* __restrict__ Pm, const float* __restrict__ Ps,
                          float* __restrict__ rv) {
  int j = blockIdx.x * 256 + threadIdx.x;
  float m = Pm[j], s = Ps[j];
  for (int b = 1; b < 16; ++b)
    lse_comb(m, s, Pm[(size_t)b * 8192 + j], Ps[(size_t)b * 8192 + j]);
  rv[j] = m + log2f(s);
}

// cpos from slots 16..79; cneg from slots 80..95
__global__ void comb_cpc_k(const float* __restrict__ Pm, const float* __restrict__ Ps,
                           float* __restrict__ cpos, float* __restrict__ cneg) {
  int j = blockIdx.x * 256 + threadIdx.x;
  if (j < 8192) {
    float m = Pm[(size_t)16 * 8192 + j], s = Ps[(size_t)16 * 8192 + j];
    for (int b = 17; b < 80; ++b)
      lse_comb(m, s, Pm[(size_t)b * 8192 + j], Ps[(size_t)b * 8192 + j]);
    cpos[j] = m + log2f(s);
  } else {
    int jj = j - 8192;
    float m = Pm[(size_t)80 * 8192 + jj], s = Ps[(size_t)80 * 8192 + jj];
    for (int b = 81; b < 96; ++b)
      lse_comb(m, s, Pm[(size_t)b * 8192 + jj], Ps[(size_t)b * 8192 + jj]);
    cneg[jj] = m + log2f(s);
  }
}

// ---------- PV: Mpart[kh] = A_half[:, kh] @ B^T, plus partial rowsum(A) ----------
template <bool NEG>
__global__ __launch_bounds__(512) void pv_k(
    const u16* __restrict__ DqPos, const u16* __restrict__ DqTri,
    const float* __restrict__ rvec, const float* __restrict__ w,
    const u16* __restrict__ BT, float* __restrict__ Mout,
    float* __restrict__ sout) {
  const int tid = threadIdx.x, lane = tid & 63, wave = tid >> 6;
  const int I = blockIdx.y;   // 64-row stripe
  const int kh = blockIdx.x;  // K half: j in [kh*4096, +4096)
  __shared__ __align__(16) u16 AT[64 * 128];
  __shared__ __align__(16) u16 Bs[4 * 256 * 32];
  __shared__ __align__(16) u16 stg[NEG ? 2 * 4096 : 8];
  __shared__ float rvS[64];
  __shared__ float SredN[64][8];
  __shared__ float SredT[64][8];
  const int wrg = (wave >> 2) * 32, wcg = (wave & 3) * 64;
  const int fr = lane & 15, ko = (lane >> 4) * 8;
  const int rn = tid >> 3;          // 0..63 (natural A-build row)
  const int cnp = (tid & 7) * 16;   // pos: 16 cols/thread
  const int cnn = (tid & 7) * 8;    // neg natural/stage: 8 cols/thread
  const int swr = (rn & 7) << 3;
  const int p = tid & 63, sjg = tid >> 6;  // transposed read org
  const int swp = (p & 7) << 3;
  float asumN = 0.f, asumT = 0.f;
  if (tid < 64) rvS[tid] = rvec[I * 64 + tid];
  __syncthreads();
  const float riN = rvS[rn];
  const float riT = rvS[p];
  f32x4 acc[2][4] = {};

  for (int jc = 0; jc < 32; ++jc) {
    const int j0 = (kh * 32 + jc) * 128;
    __syncthreads();  // guard AT/Bs/stg overwrite vs previous MFMA/stg reads
#pragma unroll
    for (int ks = 0; ks < 4; ++ks) {
      int brow = wave * 32 + (lane >> 2);
      int bcol = (lane & 3) * 8;
      gload16(BT + (size_t)brow * 8192 + j0 + ks * 32 + bcol,
              Bs + ks * 8192 + wave * 32 * 32);
      gload16(BT + (size_t)(brow + 16) * 8192 + j0 + ks * 32 + bcol,
              Bs + ks * 8192 + (wave * 32 + 16) * 32);
    }
    if constexpr (!NEG) {
      const u16* rp = DqPos + (size_t)(I * 64 + rn) * 8192 + j0 + cnp;
      u16x8 qa = *(const u16x8*)rp;
      u16x8 qb = *(const u16x8*)(rp + 8);
      const float* wp = w + j0 + cnp;
      f32x4 w0 = *(const f32x4*)wp;
      f32x4 w1 = *(const f32x4*)(wp + 4);
      f32x4 w2 = *(const f32x4*)(wp + 8);
      f32x4 w3 = *(const f32x4*)(wp + 12);
      union { u16x8 v; u16 e[8]; } pk0, pk1;
#pragma unroll
      for (int e = 0; e < 4; ++e) {
        float a0 = exp2f(fmaf((float)qa[e], -INVQ, -riN - w0[e]));
        float a1 = exp2f(fmaf((float)qa[4 + e], -INVQ, -riN - w1[e]));
        float a2 = exp2f(fmaf((float)qb[e], -INVQ, -riN - w2[e]));
        float a3 = exp2f(fmaf((float)qb[4 + e], -INVQ, -riN - w3[e]));
        asumN += a0 + a1 + a2 + a3;
        pk0.e[e] = f2bf(a0); pk0.e[4 + e] = f2bf(a1);
        pk1.e[e] = f2bf(a2); pk1.e[4 + e] = f2bf(a3);
      }
      *(u16x8*)&AT[rn * 128 + (cnp ^ swr)] = pk0.v;
      *(u16x8*)&AT[rn * 128 + ((cnp + 8) ^ swr)] = pk1.v;
    } else {
      bool anytr = false;
#pragma unroll
      for (int h = 0; h < 2; ++h) {
        const int Jb = kh * 64 + jc * 2 + h;
        if (Jb <= I) {
          const u16* blk = DqTri + triblk(I, Jb);
          u16x8 q = *(const u16x8*)&blk[rn * 64 + cnn];
          const float* wp = w + Jb * 64 + cnn;
          f32x4 w0 = *(const f32x4*)wp;
          f32x4 w1 = *(const f32x4*)(wp + 4);
          union { u16x8 v; u16 e[8]; } pk;
#pragma unroll
          for (int e = 0; e < 4; ++e) {
            float a0 = exp2f(fmaf((float)q[e], -INVQ, -riN - w0[e]));
            float a1 = exp2f(fmaf((float)q[4 + e], -INVQ, -riN - w1[e]));
            asumN += a0 + a1;
            pk.e[e] = f2bf(a0); pk.e[4 + e] = f2bf(a1);
          }
          *(u16x8*)&AT[rn * 128 + ((h * 64 + cnn) ^ swr)] = pk.v;
        } else {
          anytr = true;
          const u16* blk = DqTri + triblk(Jb, I);
          u16x8 q = *(const u16x8*)&blk[rn * 64 + cnn];
          *(u16x8*)&stg[h * 4096 + rn * 64 + (cnn ^ swr)] = q;
        }
      }
      if (anytr) {
        __syncthreads();
#pragma unroll
        for (int h = 0; h < 2; ++h) {
          const int Jb = kh * 64 + jc * 2 + h;
          if (Jb <= I) continue;
#pragma unroll
          for (int cc = 0; cc < 8; ++cc) {
            int sj = cc * 8 + sjg;
            u16 q = stg[h * 4096 + sj * 64 + (p ^ ((sj & 7) << 3))];
            float a = exp2f(fmaf((float)q, -INVQ, -riT - w[Jb * 64 + sj]));
            asumT += a;
            AT[p * 128 + ((h * 64 + sj) ^ swp)] = f2bf(a);
          }
        }
      }
    }
    __syncthreads();  // AT + Bs (gload drained) ready
#pragma unroll
    for (int ks = 0; ks < 4; ++ks) {
      bf16x8 a2[2], b2[4];
#pragma unroll
      for (int m = 0; m < 2; ++m) {
        int rl = wrg + m * 16 + fr;
        a2[m] = *(const bf16x8*)&AT[rl * 128 + ((ks * 32 + ko) ^ ((rl & 7) << 3))];
      }
#pragma unroll
      for (int n = 0; n < 4; ++n)
        b2[n] = *(const bf16x8*)&Bs[ks * 8192 + (wcg + n * 16 + fr) * 32 + ko];
#pragma unroll
      for (int m = 0; m < 2; ++m)
#pragma unroll
        for (int n = 0; n < 4; ++n)
          acc[m][n] = __builtin_amdgcn_mfma_f32_16x16x32_bf16(a2[m], b2[n], acc[m][n], 0, 0, 0);
    }
  }
  // write M partial
#pragma unroll
  for (int m = 0; m < 2; ++m)
#pragma unroll
    for (int n = 0; n < 4; ++n)
#pragma unroll
      for (int q = 0; q < 4; ++q) {
        int row = I * 64 + wrg + m * 16 + (lane >> 4) * 4 + q;
        int d = wcg + n * 16 + fr;
        Mout[(size_t)kh * 2097152 + (size_t)row * 256 + d] = acc[m][n][q];
      }
  // partial rowsum(A)
  SredN[rn][tid & 7] = asumN;
  SredT[p][sjg] = NEG ? asumT : 0.f;
  __syncthreads();
  if (tid < 64) {
    float s = 0.f;
#pragma unroll
    for (int b = 0; b < 8; ++b) s += SredN[tid][b] + SredT[tid][b];
    sout[kh * 8192 + I * 64 + tid] = s;
  }
}

// ---------- elementwise / transpose / norms ----------
__global__ void convert_split_k(const float* __restrict__ src, u16* __restrict__ hi,
                                u16* __restrict__ lo, int n) {
  int i = blockIdx.x * 256 + threadIdx.x;
  if (i < n) {
    float v = src[i];
    u16 h = f2bf(v);
    hi[i] = h;
    lo[i] = f2bf(v - bf2f(h));
  }
}

__global__ void transpose_split_k(const float* __restrict__ src, int K, int N,
                                  u16* __restrict__ hi, u16* __restrict__ lo) {
  __shared__ float t[32][33];
  int x = threadIdx.x & 31, y = threadIdx.x >> 5;
  int k0 = blockIdx.x * 32, n0 = blockIdx.y * 32;
  for (int yy = y; yy < 32; yy += 8) t[yy][x] = src[(size_t)(k0 + yy) * N + n0 + x];
  __syncthreads();
  for (int yy = y; yy < 32; yy += 8) {
    float v = t[x][yy];
    size_t idx = (size_t)(n0 + yy) * K + k0 + x;
    u16 h = f2bf(v);
    hi[idx] = h;
    lo[idx] = f2bf(v - bf2f(h));
  }
}

__global__ void transpose_b16_k(const float* __restrict__ src, int M, int D,
                                u16* __restrict__ dst) {
  __shared__ float t[32][33];
  int x = threadIdx.x & 31, y = threadIdx.x >> 5;
  int m0 = blockIdx.x * 32, d0 = blockIdx.y * 32;
  for (int yy = y; yy < 32; yy += 8) t[yy][x] = src[(size_t)(m0 + yy) * D + d0 + x];
  __syncthreads();
  for (int yy = y; yy < 32; yy += 8)
    dst[(size_t)(d0 + yy) * M + m0 + x] = f2bf(t[x][yy]);
}

__global__ void rownorm_k(const float* __restrict__ src, float* __restrict__ o) {
  int i = blockIdx.x, t = threadIdx.x;
  float s = 0.f;
  for (int d = t; d < 256; d += 64) {
    float v = src[(size_t)i * 256 + d];
    s += v * v;
  }
  for (int off = 32; off; off >>= 1) s += __shfl_down(s, off, 64);
  if (t == 0) o[i] = s;
}

__global__ void zero_k(float* __restrict__ p, int n) {
  int i = blockIdx.x * 256 + threadIdx.x;
  if (i < n) p[i] = 0.f;
}

__global__ void decode_k(float* __restrict__ out, float x, int n) {
  int i = blockIdx.x * 256 + threadIdx.x;
  if (i < n) out[i] = x;
}

__global__ void final_out_k(const float* __restrict__ M1, const float* __restrict__ M2,
                            const float* __restrict__ sp, const float* __restrict__ sn,
                            float* __restrict__ out) {
  __shared__ float S[256];
  int i = blockIdx.x, d = threadIdx.x;
  size_t idx = (size_t)i * 256 + d;
  float spv = sp[i] + sp[8192 + i];
  float snv = sn[i] + sn[8192 + i];
  float v = snv * (M1[idx] + M1[2097152 + idx]) - spv * (M2[idx] + M2[2097152 + idx]);
  S[d] = v * v;
  __syncthreads();
  for (int off = 128; off; off >>= 1) {
    if (d < off) S[d] += S[d + off];
    __syncthreads();
  }
  if (d == 0) out[i] = S[0];
}

// ---------- host ----------
extern "C" void kernel_launch(void* const* d_in, const int* in_sizes, int n_in,
                              void* d_out, int out_size, void* d_ws, size_t ws_size,
                              hipStream_t stream) {
  (void)in_sizes; (void)n_in; (void)out_size;
  const float* pos = (const float*)d_in[0];
  const float* z   = (const float*)d_in[1];
  const float* W1  = (const float*)d_in[2];
  const float* b1  = (const float*)d_in[3];
  const float* W2  = (const float*)d_in[4];
  const float* b2  = (const float*)d_in[5];
  const float* W3  = (const float*)d_in[6];
  const float* b3  = (const float*)d_in[7];
  const float* W4  = (const float*)d_in[8];
  const float* b4  = (const float*)d_in[9];
  const float* W5  = (const float*)d_in[10];
  const float* b5  = (const float*)d_in[11];
  float* out = (float*)d_out;

  if (ws_size < (size_t)261500000) {
    decode_k<<<32, 256, 0, stream>>>(out, (float)(double)(ws_size >> 10), 8192);
    return;
  }

  char* wsp = (char*)d_ws;
  size_t off = 0;
  auto alloc = [&](size_t bytes) -> char* {
    char* p = wsp + off;
    off += (bytes + 255) & ~(size_t)255;
    return p;
  };
  u16* DqPos = (u16*)alloc((size_t)8192 * 8192 * 2);  // 134.2 MB
  u16* DqTri = (u16*)alloc((size_t)8256 * 4096 * 2);  // 67.6 MB (lower block-triangle)
  u16* Yh    = (u16*)alloc((size_t)16384 * 256 * 2);  // pos rows [0:8192), gen [8192:)
  u16* Yl    = (u16*)alloc((size_t)16384 * 256 * 2);
  u16* posT  = (u16*)alloc((size_t)256 * 8192 * 2);
  u16* genT  = (u16*)alloc((size_t)256 * 8192 * 2);
  float* yN2 = (float*)alloc(16384 * 4);
  float* rv  = (float*)alloc(8192 * 4);
  float* cpos = (float*)alloc(8192 * 4);
  float* cneg = (float*)alloc(8192 * 4);
  float* spv = (float*)alloc(2 * 8192 * 4);
  float* snv = (float*)alloc(2 * 8192 * 4);
  float* M1  = (float*)alloc((size_t)2 * 8192 * 256 * 4);  // K-split partials (16.8 MB)
  float* M2  = (float*)alloc((size_t)2 * 8192 * 256 * 4);
  // Pm/Ps (PSLOTS x 8192 f32 = 3.15 MB each) alias M1: dead before pv_k writes M1
  float* Pm = M1;
  float* Ps = Pm + (size_t)PSLOTS * 8192;

  // transient MLP arena aliases DqPos (~94 MB < 134 MB; dead before DqPos written)
  size_t toff = 0;
  char* tbase = (char*)DqPos;
  auto talloc = [&](size_t bytes) -> char* {
    char* p = tbase + toff;
    toff += (bytes + 255) & ~(size_t)255;
    return p;
  };
  u16* zh    = (u16*)talloc((size_t)8192 * 128 * 2);
  u16* zl    = (u16*)talloc((size_t)8192 * 128 * 2);
  u16* W1Th  = (u16*)talloc(1024 * 128 * 2);
  u16* W1Tl  = (u16*)talloc(1024 * 128 * 2);
  u16* W2Th  = (u16*)talloc(1024 * 1024 * 2);
  u16* W2Tl  = (u16*)talloc(1024 * 1024 * 2);
  u16* W3Th  = (u16*)talloc(1024 * 1024 * 2);
  u16* W3Tl  = (u16*)talloc(1024 * 1024 * 2);
  u16* W4Th  = (u16*)talloc(1024 * 1024 * 2);
  u16* W4Tl  = (u16*)talloc(1024 * 1024 * 2);
  u16* W5Th  = (u16*)talloc(256 * 1024 * 2);
  u16* W5Tl  = (u16*)talloc(256 * 1024 * 2);
  u16* h1h   = (u16*)talloc((size_t)8192 * 1024 * 2);
  u16* h1l   = (u16*)talloc((size_t)8192 * 1024 * 2);
  u16* h2h   = (u16*)talloc((size_t)8192 * 1024 * 2);
  u16* h2l   = (u16*)talloc((size_t)8192 * 1024 * 2);
  float* genf = (float*)talloc((size_t)8192 * 256 * 4);

  u16* genH = Yh + (size_t)8192 * 256;
  u16* genL = Yl + (size_t)8192 * 256;
  float* pN2 = yN2;
  float* gN2 = yN2 + 8192;

  // ---- preprocessing ----
  convert_split_k<<<4096, 256, 0, stream>>>(z, zh, zl, 8192 * 128);
  convert_split_k<<<8192, 256, 0, stream>>>(pos, Yh, Yl, 8192 * 256);
  transpose_split_k<<<dim3(4, 32), 256, 0, stream>>>(W1, 128, 1024, W1Th, W1Tl);
  transpose_split_k<<<dim3(32, 32), 256, 0, stream>>>(W2, 1024, 1024, W2Th, W2Tl);
  transpose_split_k<<<dim3(32, 32), 256, 0, stream>>>(W3, 1024, 1024, W3Th, W3Tl);
  transpose_split_k<<<dim3(32, 32), 256, 0, stream>>>(W4, 1024, 1024, W4Th, W4Tl);
  transpose_split_k<<<dim3(32, 8), 256, 0, stream>>>(W5, 1024, 256, W5Th, W5Tl);
  rownorm_k<<<8192, 64, 0, stream>>>(pos, pN2);
  transpose_b16_k<<<dim3(256, 8), 256, 0, stream>>>(pos, 8192, 256, posT);

  // ---- MLP (split-bf16, fused bias+selu; 64x128 tiles for occupancy) ----
  gemm_k<64, 128, 2, 2, EPI_MLP><<<dim3(8, 128), 256, 0, stream>>>(
      zh, zl, 128, W1Th, W1Tl, 128, 128, nullptr, 0, b1, 1, h1h, h1l, 1024,
      nullptr, nullptr, nullptr);
  gemm_k<64, 128, 2, 2, EPI_MLP><<<dim3(8, 128), 256, 0, stream>>>(
      h1h, h1l, 1024, W2Th, W2Tl, 1024, 1024, nullptr, 0, b2, 1, h2h, h2l, 1024,
      nullptr, nullptr, nullptr);
  gemm_k<64, 128, 2, 2, EPI_MLP><<<dim3(8, 128), 256, 0, stream>>>(
      h2h, h2l, 1024, W3Th, W3Tl, 1024, 1024, nullptr, 0, b3, 1, h1h, h1l, 1024,
      nullptr, nullptr, nullptr);
  gemm_k<64, 128, 2, 2, EPI_MLP><<<dim3(8, 128), 256, 0, stream>>>(
      h1h, h1l, 1024, W4Th, W4Tl, 1024, 1024, nullptr, 0, b4, 1, h2h, h2l, 1024,
      nullptr, nullptr, nullptr);
  gemm_k<64, 128, 2, 2, EPI_MLP><<<dim3(2, 128), 256, 0, stream>>>(
      h2h, h2l, 1024, W5Th, W5Tl, 1024, 1024, genf, 256, b5, 0,
      genH, genL, 256, nullptr, nullptr, nullptr);

  rownorm_k<<<8192, 64, 0, stream>>>(genf, gN2);
  transpose_b16_k<<<dim3(256, 8), 256, 0, stream>>>(genf, 8192, 256, genT);

  // ---- build stored distance matrices (un-fused; transients dead) ----
  gemm_k<128, 128, 2, 2, EPI_DISTQ><<<4096, 256, 0, stream>>>(
      genH, genL, 256, Yh, Yl, 256, 256, nullptr, 0, nullptr, 0, nullptr,
      nullptr, 0, gN2, pN2, DqPos);
  gemm_k<128, 128, 2, 2, EPI_NEGTRI><<<2080, 256, 0, stream>>>(
      genH, genL, 256, genH, genL, 256, 256, nullptr, 0, nullptr, 0, nullptr,
      nullptr, 0, gN2, gN2, DqTri);

  // ---- Sinkhorn (log2 domain): 5 x {row, col}, 16-chunk grids for occupancy ----
  zero_k<<<64, 256, 0, stream>>>(cpos, 16384);  // cpos + cneg (contiguous)
  for (int it = 0; it < 5; ++it) {
    sink_k<<<dim3(16, 128), 256, 0, stream>>>(DqPos, DqTri, cpos, cneg, Pm, Ps);
    comb_rv_k<<<32, 256, 0, stream>>>(Pm, Ps, rv);
    colpass_k<<<2560, 256, 0, stream>>>(DqPos, DqTri, rv, Pm, Ps);
    comb_cpc_k<<<64, 256, 0, stream>>>(Pm, Ps, cpos, cneg);
  }

  // ---- PV from stored Dq (K-split x2, partial M/s) ----
  pv_k<false><<<dim3(2, 128), 512, 0, stream>>>(DqPos, DqTri, rv, cpos, posT, M1, spv);
  pv_k<true><<<dim3(2, 128), 512, 0, stream>>>(DqPos, DqTri, rv, cneg, genT, M2, snv);

  // ---- out_i = sum_d (sn_i*(M1a+M1b) - sp_i*(M2a+M2b))^2 ----
  final_out_k<<<8192, 256, 0, stream>>>(M1, M2, spv, snv, out);
}

// Round 15
// 1405.885 us; speedup vs baseline: 1.1071x; 1.0261x over previous
//
#include <hip/hip_runtime.h>

#define DEVI __device__ __forceinline__

typedef short bf16x8 __attribute__((ext_vector_type(8)));
typedef float f32x4 __attribute__((ext_vector_type(4)));
typedef unsigned short u16;
typedef unsigned short u16x8 __attribute__((ext_vector_type(8)));
typedef unsigned short u16x4 __attribute__((ext_vector_type(4)));

enum { EPI_MLP = 0, EPI_DISTQ = 1, EPI_NEGTRI = 2 };

#define KLOG2E_T 28.853900817779268f /* log2(e)/TEMP */
#define QSCALE 1846.6496523378733f   /* KLOG2E_T * 64 */
#define INVQ 0.015625f               /* 1/64 */
#define PSLOTS 80                    /* 0..7 row, 8..71 pos-col, 72..79 neg-col */

// ---------- small helpers ----------
DEVI u16 f2bf(float f) {
  unsigned u = __float_as_uint(f);
  return (u16)((u + 0x7FFFu + ((u >> 16) & 1u)) >> 16);
}
DEVI float bf2f(u16 h) { return __uint_as_float(((unsigned)h) << 16); }
DEVI float seluf(float x) {
  return x > 0.f ? 1.0507009873554805f * x : 1.7580993408473766f * expm1f(x);
}
DEVI void gload16(const void* g, void* l) {
  __builtin_amdgcn_global_load_lds(
      (const __attribute__((address_space(1))) unsigned*)g,
      (__attribute__((address_space(3))) unsigned*)l, 16, 0, 0);
}
DEVI void lse_comb(float& m, float& s, float m2, float s2) {
  float M = fmaxf(m, m2);
  s = s * exp2f(m - M) + s2 * exp2f(m2 - M);
  m = M;
}
DEVI size_t triblk(int I, int J) { return ((size_t)I * (I + 1) / 2 + J) * 4096; }

// ---------- GEMM: C = A * B^T, split-bf16 (hi+lo, 3 MFMA); hoisted-pointer staging ----------
template <int BM, int BN, int WM, int WN, int EPI>
__global__ __launch_bounds__(WM* WN * 64) void gemm_k(
    const u16* __restrict__ Ahi, const u16* __restrict__ Alo, int lda,
    const u16* __restrict__ Bhi, const u16* __restrict__ Blo, int ldb, int K,
    float* __restrict__ Cf, int ldc,
    const float* __restrict__ bias, int act, u16* __restrict__ Ohi,
    u16* __restrict__ Olo, int ldo,
    const float* __restrict__ xN2, const float* __restrict__ yN2,
    u16* __restrict__ Cq) {
  constexpr int NW = WM * WN;
  constexpr int FM = BM / (WM * 16), FN = BN / (WN * 16);
  constexpr int IA = BM / (16 * NW), IB = BN / (16 * NW);
  const int tid = threadIdx.x, lane = tid & 63, wave = tid >> 6;
  int bm0, bn0;
  if constexpr (EPI == EPI_DISTQ) {
    // L2 super-tile swizzle: XCD (bid&7) walks 8x8-block super-tiles (~2MB set -> L2-fit)
    int bid = (int)blockIdx.x;
    int xcd = bid & 7, p = bid >> 3;
    int st = (p >> 6) * 8 + xcd;
    int r8 = (p >> 3) & 7, c8 = p & 7;
    bm0 = ((st >> 3) * 8 + r8) * 128;
    bn0 = ((st & 7) * 8 + c8) * 128;
  } else if constexpr (EPI == EPI_NEGTRI) {
    // compact lower block-triangle: 2080 tiles of 128^2
    int t = (int)blockIdx.x;
    int a = (int)((sqrtf(8.f * (float)t + 1.f) - 1.f) * 0.5f);
    while ((a + 1) * (a + 2) / 2 <= t) ++a;
    while (a * (a + 1) / 2 > t) --a;
    int b = t - a * (a + 1) / 2;
    bm0 = a * 128;
    bn0 = b * 128;
  } else {
    bm0 = blockIdx.y * BM;
    bn0 = blockIdx.x * BN;
  }
  const int wr = (wave / WN) * (FM * 16), wc = (wave % WN) * (FN * 16);
  __shared__ __align__(16) u16 AsH[BM * 32];
  __shared__ __align__(16) u16 BsH[BN * 32];
  __shared__ __align__(16) u16 AsL[BM * 32];
  __shared__ __align__(16) u16 BsL[BN * 32];
  // hoisted staging pointers: stepped +32 per k-iter
  const int srow = lane >> 2, scol = (lane & 3) * 8;
  const u16 *pAh[IA], *pAl[IA], *pBh[IB], *pBl[IB];
  int lA[IA], lB[IB];
#pragma unroll
  for (int t = 0; t < IA; ++t) {
    int r = (wave * IA + t) * 16;
    pAh[t] = Ahi + (size_t)(bm0 + r + srow) * lda + scol;
    pAl[t] = Alo + (size_t)(bm0 + r + srow) * lda + scol;
    lA[t] = r * 32;
  }
#pragma unroll
  for (int t = 0; t < IB; ++t) {
    int r = (wave * IB + t) * 16;
    pBh[t] = Bhi + (size_t)(bn0 + r + srow) * ldb + scol;
    pBl[t] = Blo + (size_t)(bn0 + r + srow) * ldb + scol;
    lB[t] = r * 32;
  }
  f32x4 acc[FM][FN] = {};
  const int fr = lane & 15, ko = (lane >> 4) * 8;
  for (int k0 = 0; k0 < K; k0 += 32) {
#pragma unroll
    for (int t = 0; t < IA; ++t) {
      gload16(pAh[t], AsH + lA[t]); pAh[t] += 32;
      gload16(pAl[t], AsL + lA[t]); pAl[t] += 32;
    }
#pragma unroll
    for (int t = 0; t < IB; ++t) {
      gload16(pBh[t], BsH + lB[t]); pBh[t] += 32;
      gload16(pBl[t], BsL + lB[t]); pBl[t] += 32;
    }
    __syncthreads();
    bf16x8 ah[FM], bh[FN], al[FM], bl[FN];
#pragma unroll
    for (int m = 0; m < FM; ++m) ah[m] = *(const bf16x8*)&AsH[(wr + m * 16 + fr) * 32 + ko];
#pragma unroll
    for (int n = 0; n < FN; ++n) bh[n] = *(const bf16x8*)&BsH[(wc + n * 16 + fr) * 32 + ko];
#pragma unroll
    for (int m = 0; m < FM; ++m) al[m] = *(const bf16x8*)&AsL[(wr + m * 16 + fr) * 32 + ko];
#pragma unroll
    for (int n = 0; n < FN; ++n) bl[n] = *(const bf16x8*)&BsL[(wc + n * 16 + fr) * 32 + ko];
#pragma unroll
    for (int m = 0; m < FM; ++m)
#pragma unroll
      for (int n = 0; n < FN; ++n) {
        acc[m][n] = __builtin_amdgcn_mfma_f32_16x16x32_bf16(ah[m], bh[n], acc[m][n], 0, 0, 0);
        acc[m][n] = __builtin_amdgcn_mfma_f32_16x16x32_bf16(al[m], bh[n], acc[m][n], 0, 0, 0);
        acc[m][n] = __builtin_amdgcn_mfma_f32_16x16x32_bf16(ah[m], bl[n], acc[m][n], 0, 0, 0);
      }
    __syncthreads();
  }
#pragma unroll
  for (int m = 0; m < FM; ++m)
#pragma unroll
    for (int n = 0; n < FN; ++n)
#pragma unroll
      for (int q = 0; q < 4; ++q) {
        int row = bm0 + wr + m * 16 + (lane >> 4) * 4 + q;
        int col = bn0 + wc + n * 16 + fr;
        float v = acc[m][n][q];
        if constexpr (EPI == EPI_MLP) {
          v += bias[col];
          if (act) v = seluf(v);
          u16 h = f2bf(v);
          size_t idx = (size_t)row * ldo + col;
          Ohi[idx] = h;
          Olo[idx] = f2bf(v - bf2f(h));
          if (Cf) Cf[(size_t)row * ldc + col] = v;
        } else if constexpr (EPI == EPI_DISTQ) {
          float d2 = fmaxf(xN2[row] + yN2[col] - 2.f * v, 0.f);
          float qf = fminf(QSCALE * sqrtf(d2), 65535.f);
          Cq[(size_t)row * 8192 + col] = (u16)__float2uint_rn(qf);
        } else {  // EPI_NEGTRI
          int bI = row >> 6, bJ = col >> 6;
          if (bJ <= bI) {
            float d2 = fmaxf(xN2[row] + yN2[col] - 2.f * v, 0.f);
            float qf = fminf(QSCALE * sqrtf(d2), 65535.f);
            u16 qu = (u16)__float2uint_rn(qf);
            if (row == col) qu = 65535;
            Cq[triblk(bI, bJ) + (row & 63) * 64 + (col & 63)] = qu;
          }
        }
      }
}

// ---------- shared LSE micro-op ----------
DEVI void lse16(const u16x8& qa, const u16x8& qb, const float* __restrict__ w,
                float& m, float& s) {
  f32x4 w0 = *(const f32x4*)w;
  f32x4 w1 = *(const f32x4*)(w + 4);
  f32x4 w2 = *(const f32x4*)(w + 8);
  f32x4 w3 = *(const f32x4*)(w + 12);
  float v[16];
#pragma unroll
  for (int e = 0; e < 4; ++e) {
    v[e] = fmaf((float)qa[e], -INVQ, -w0[e]);
    v[4 + e] = fmaf((float)qa[4 + e], -INVQ, -w1[e]);
    v[8 + e] = fmaf((float)qb[e], -INVQ, -w2[e]);
    v[12 + e] = fmaf((float)qb[4 + e], -INVQ, -w3[e]);
  }
  float mx = v[0];
#pragma unroll
  for (int e = 1; e < 16; ++e) mx = fmaxf(mx, v[e]);
  float ac = 0.f;
#pragma unroll
  for (int e = 0; e < 16; ++e) ac += exp2f(v[e] - mx);
  lse_comb(m, s, mx, ac);
}

// ---------- Sinkhorn row-LSE: stripe of 64 rows, EIGHTH of j-range ----------
__global__ __launch_bounds__(256) void sink_k(
    const u16* __restrict__ DqPos, const u16* __restrict__ DqTri,
    const float* __restrict__ wpos, const float* __restrict__ wneg,
    float* __restrict__ Pm, float* __restrict__ Ps) {
  const int tid = threadIdx.x;
  const int I = blockIdx.y, q8 = blockIdx.x;
  __shared__ __align__(16) u16 stg[4096];
  __shared__ float Cm[64][12], Cs[64][12];
  const int rn = tid >> 2, cn = (tid & 3) * 16;  // natural org: 4 thr/row
  const int p2 = tid & 31, g8 = tid >> 5;        // transposed org
  float mA = -3.0e38f, sA = 0.f;
  float mB0 = -3.0e38f, sB0 = 0.f, mB1 = -3.0e38f, sB1 = 0.f;
  const int sw = (rn & 7) << 3;

  {
    const size_t rowbase = (size_t)(I * 64 + rn) * 8192;
    for (int jc = 0; jc < 16; ++jc) {
      int j0 = q8 * 1024 + jc * 64 + cn;
      u16x8 qa = *(const u16x8*)&DqPos[rowbase + j0];
      u16x8 qb = *(const u16x8*)&DqPos[rowbase + j0 + 8];
      lse16(qa, qb, wpos + j0, mA, sA);
    }
  }
  for (int Jb = q8 * 16; Jb < q8 * 16 + 16; ++Jb) {
    if (Jb <= I) {
      const u16* blk = DqTri + triblk(I, Jb);
      u16x8 qa = *(const u16x8*)&blk[rn * 64 + cn];
      u16x8 qb = *(const u16x8*)&blk[rn * 64 + cn + 8];
      lse16(qa, qb, wneg + Jb * 64 + cn, mA, sA);
    } else {
      const u16* blk = DqTri + triblk(Jb, I);
      u16x8 qa = *(const u16x8*)&blk[rn * 64 + cn];
      u16x8 qb = *(const u16x8*)&blk[rn * 64 + cn + 8];
      *(u16x8*)&stg[rn * 64 + (cn ^ sw)] = qa;
      *(u16x8*)&stg[rn * 64 + ((cn + 8) ^ sw)] = qb;
      __syncthreads();
      float v0[8], v1[8];
#pragma unroll
      for (int cc = 0; cc < 8; ++cc) {
        int sj = cc * 8 + g8;
        unsigned wq = *(const unsigned*)&stg[sj * 64 + ((2 * p2) ^ ((sj & 7) << 3))];
        float wgt = wneg[Jb * 64 + sj];
        v0[cc] = fmaf((float)(wq & 0xFFFFu), -INVQ, -wgt);
        v1[cc] = fmaf((float)(wq >> 16), -INVQ, -wgt);
      }
      float mx0 = v0[0], mx1 = v1[0];
#pragma unroll
      for (int cc = 1; cc < 8; ++cc) { mx0 = fmaxf(mx0, v0[cc]); mx1 = fmaxf(mx1, v1[cc]); }
      float a0 = 0.f, a1 = 0.f;
#pragma unroll
      for (int cc = 0; cc < 8; ++cc) { a0 += exp2f(v0[cc] - mx0); a1 += exp2f(v1[cc] - mx1); }
      lse_comb(mB0, sB0, mx0, a0);
      lse_comb(mB1, sB1, mx1, a1);
      __syncthreads();
    }
  }
  for (int i = tid; i < 64 * 12; i += 256) { (&Cm[0][0])[i] = -3.0e38f; (&Cs[0][0])[i] = 0.f; }
  __syncthreads();
  Cm[rn][tid & 3] = mA; Cs[rn][tid & 3] = sA;
  Cm[2 * p2][4 + g8] = mB0; Cs[2 * p2][4 + g8] = sB0;
  Cm[2 * p2 + 1][4 + g8] = mB1; Cs[2 * p2 + 1][4 + g8] = sB1;
  __syncthreads();
  if (tid < 64) {
    float m = Cm[tid][0], s = Cs[tid][0];
#pragma unroll
    for (int b = 1; b < 12; ++b) lse_comb(m, s, Cm[tid][b], Cs[tid][b]);
    Pm[(size_t)q8 * 8192 + I * 64 + tid] = m;
    Ps[(size_t)q8 * 8192 + I * 64 + tid] = s;
  }
}

// ---------- col pass: neg chunks (0..1023) + pos-col blocks (1024..1535) ----------
__global__ __launch_bounds__(256) void colpass_k(
    const u16* __restrict__ DqPos, const u16* __restrict__ DqTri,
    const float* __restrict__ rv, float* __restrict__ Pm, float* __restrict__ Ps) {
  const int bid = blockIdx.x, tid = threadIdx.x;
  __shared__ __align__(16) u16 stg[4096];
  __shared__ float Cm[64][12], Cs[64][12];
  if (bid < 1024) {
    const int q8 = bid & 7, I = bid >> 3;
    const int rn = tid >> 2, cn = (tid & 3) * 16;
    const int p2 = tid & 31, g8 = tid >> 5;
    const int sw = (rn & 7) << 3;
    float mA = -3.0e38f, sA = 0.f;
    float mB0 = -3.0e38f, sB0 = 0.f, mB1 = -3.0e38f, sB1 = 0.f;
    for (int Jb = q8 * 16; Jb < q8 * 16 + 16; ++Jb) {
      if (Jb <= I) {
        const u16* blk = DqTri + triblk(I, Jb);
        u16x8 qa = *(const u16x8*)&blk[rn * 64 + cn];
        u16x8 qb = *(const u16x8*)&blk[rn * 64 + cn + 8];
        lse16(qa, qb, rv + Jb * 64 + cn, mA, sA);
      } else {
        const u16* blk = DqTri + triblk(Jb, I);
        u16x8 qa = *(const u16x8*)&blk[rn * 64 + cn];
        u16x8 qb = *(const u16x8*)&blk[rn * 64 + cn + 8];
        *(u16x8*)&stg[rn * 64 + (cn ^ sw)] = qa;
        *(u16x8*)&stg[rn * 64 + ((cn + 8) ^ sw)] = qb;
        __syncthreads();
        float v0[8], v1[8];
#pragma unroll
        for (int cc = 0; cc < 8; ++cc) {
          int sj = cc * 8 + g8;
          unsigned wq = *(const unsigned*)&stg[sj * 64 + ((2 * p2) ^ ((sj & 7) << 3))];
          float wgt = rv[Jb * 64 + sj];
          v0[cc] = fmaf((float)(wq & 0xFFFFu), -INVQ, -wgt);
          v1[cc] = fmaf((float)(wq >> 16), -INVQ, -wgt);
        }
        float mx0 = v0[0], mx1 = v1[0];
#pragma unroll
        for (int cc = 1; cc < 8; ++cc) { mx0 = fmaxf(mx0, v0[cc]); mx1 = fmaxf(mx1, v1[cc]); }
        float a0 = 0.f, a1 = 0.f;
#pragma unroll
        for (int cc = 0; cc < 8; ++cc) { a0 += exp2f(v0[cc] - mx0); a1 += exp2f(v1[cc] - mx1); }
        lse_comb(mB0, sB0, mx0, a0);
        lse_comb(mB1, sB1, mx1, a1);
        __syncthreads();
      }
    }
    for (int i = tid; i < 64 * 12; i += 256) { (&Cm[0][0])[i] = -3.0e38f; (&Cs[0][0])[i] = 0.f; }
    __syncthreads();
    Cm[rn][tid & 3] = mA; Cs[rn][tid & 3] = sA;
    Cm[2 * p2][4 + g8] = mB0; Cs[2 * p2][4 + g8] = sB0;
    Cm[2 * p2 + 1][4 + g8] = mB1; Cs[2 * p2 + 1][4 + g8] = sB1;
    __syncthreads();
    if (tid < 64) {
      float m = Cm[tid][0], s = Cs[tid][0];
#pragma unroll
      for (int b2 = 1; b2 < 12; ++b2) lse_comb(m, s, Cm[tid][b2], Cs[tid][b2]);
      Pm[(size_t)(72 + q8) * 8192 + I * 64 + tid] = m;
      Ps[(size_t)(72 + q8) * 8192 + I * 64 + tid] = s;
    }
  } else {
    const int b2 = bid - 1024;
    const int jb = b2 & 7, ic = b2 >> 3;
    int j0 = jb * 1024 + tid * 4;
    int i0 = ic * 128;
    float m[4], s[4];
#pragma unroll
    for (int e = 0; e < 4; ++e) { m[e] = -3.0e38f; s[e] = 0.f; }
    for (int ib = 0; ib < 16; ++ib) {
      float v[4][8];
#pragma unroll
      for (int ii = 0; ii < 8; ++ii) {
        int i = i0 + ib * 8 + ii;
        u16x4 qv = *(const u16x4*)&DqPos[(size_t)i * 8192 + j0];
        float ri = rv[i];
#pragma unroll
        for (int e = 0; e < 4; ++e) v[e][ii] = fmaf((float)qv[e], -INVQ, -ri);
      }
#pragma unroll
      for (int e = 0; e < 4; ++e) {
        float mx = v[e][0];
#pragma unroll
        for (int ii = 1; ii < 8; ++ii) mx = fmaxf(mx, v[e][ii]);
        float ac = 0.f;
#pragma unroll
        for (int ii = 0; ii < 8; ++ii) ac += exp2f(v[e][ii] - mx);
        lse_comb(m[e], s[e], mx, ac);
      }
    }
#pragma unroll
    for (int e = 0; e < 4; ++e) {
      Pm[(size_t)(8 + ic) * 8192 + j0 + e] = m[e];
      Ps[(size_t)(8 + ic) * 8192 + j0 + e] = s[e];
    }
  }
}

// rv = LSE over row slots 0..7
__global__ void comb_rv_k(const float* __restrict__ Pm, const float* __restrict__ Ps,
                          float* __restrict__ rv) {
  int j = blockIdx.x * 256 + threadIdx.x;
  float m = Pm[j], s = Ps[j];
  for (int b = 1; b < 8; ++b)
    lse_comb(m, s, Pm[(size_t)b * 8192 + j], Ps[(size_t)b * 8192 + j]);
  rv[j] = m + log2f(s);
}

// cpos from slots 8..71; cneg from slots 72..79
__global__ void comb_cpc_k(const float* __restrict__ Pm, const float* __restrict__ Ps,
                           float* __restrict__ cpos, float* __restrict__ cneg) {
  int j = blockIdx.x * 256 + threadIdx.x;
  if (j < 8192) {
    float m = Pm[(size_t)8 * 8192 + j], s = Ps[(size_t)8 * 8192 + j];
    for (int b = 9; b < 72; ++b)
      lse_comb(m, s, Pm[(size_t)b * 8192 + j], Ps[(size_t)b * 8192 + j]);
    cpos[j] = m + log2f(s);
  } else {
    int jj = j - 8192;
    float m = Pm[(size_t)72 * 8192 + jj], s = Ps[(size_t)72 * 8192 + jj];
    for (int b = 73; b < 80; ++b)
      lse_comb(m, s, Pm[(size_t)b * 8192 + jj], Ps[(size_t)b * 8192 + jj]);
    cneg[jj] = m + log2f(s);
  }
}

// ---------- PV: Mpart[kh] = A_half[:, kh] @ B^T, plus partial rowsum(A) ----------
template <bool NEG>
__global__ __launch_bounds__(512) void pv_k(
    const u16* __restrict__ DqPos, const u16* __restrict__ DqTri,
    const float* __restrict__ rvec, const float* __restrict__ w,
    const u16* __restrict__ BT, float* __restrict__ Mout,
    float* __restrict__ sout) {
  const int tid = threadIdx.x, lane = tid & 63, wave = tid >> 6;
  const int I = blockIdx.y;   // 64-row stripe
  const int kh = blockIdx.x;  // K half: j in [kh*4096, +4096)
  __shared__ __align__(16) u16 AT[64 * 128];
  __shared__ __align__(16) u16 Bs[4 * 256 * 32];
  __shared__ __align__(16) u16 stg[NEG ? 2 * 4096 : 8];
  __shared__ float rvS[64];
  __shared__ float SredN[64][8];
  __shared__ float SredT[64][8];
  const int wrg = (wave >> 2) * 32, wcg = (wave & 3) * 64;
  const int fr = lane & 15, ko = (lane >> 4) * 8;
  const int rn = tid >> 3;          // 0..63 (natural A-build row)
  const int cnp = (tid & 7) * 16;   // pos: 16 cols/thread
  const int cnn = (tid & 7) * 8;    // neg natural/stage: 8 cols/thread
  const int swr = (rn & 7) << 3;
  const int p = tid & 63, sjg = tid >> 6;  // transposed read org
  const int swp = (p & 7) << 3;
  float asumN = 0.f, asumT = 0.f;
  if (tid < 64) rvS[tid] = rvec[I * 64 + tid];
  __syncthreads();
  const float riN = rvS[rn];
  const float riT = rvS[p];
  f32x4 acc[2][4] = {};

  for (int jc = 0; jc < 32; ++jc) {
    const int j0 = (kh * 32 + jc) * 128;
    __syncthreads();  // guard AT/Bs/stg overwrite vs previous MFMA/stg reads
#pragma unroll
    for (int ks = 0; ks < 4; ++ks) {
      int brow = wave * 32 + (lane >> 2);
      int bcol = (lane & 3) * 8;
      gload16(BT + (size_t)brow * 8192 + j0 + ks * 32 + bcol,
              Bs + ks * 8192 + wave * 32 * 32);
      gload16(BT + (size_t)(brow + 16) * 8192 + j0 + ks * 32 + bcol,
              Bs + ks * 8192 + (wave * 32 + 16) * 32);
    }
    if constexpr (!NEG) {
      const u16* rp = DqPos + (size_t)(I * 64 + rn) * 8192 + j0 + cnp;
      u16x8 qa = *(const u16x8*)rp;
      u16x8 qb = *(const u16x8*)(rp + 8);
      const float* wp = w + j0 + cnp;
      f32x4 w0 = *(const f32x4*)wp;
      f32x4 w1 = *(const f32x4*)(wp + 4);
      f32x4 w2 = *(const f32x4*)(wp + 8);
      f32x4 w3 = *(const f32x4*)(wp + 12);
      union { u16x8 v; u16 e[8]; } pk0, pk1;
#pragma unroll
      for (int e = 0; e < 4; ++e) {
        float a0 = exp2f(fmaf((float)qa[e], -INVQ, -riN - w0[e]));
        float a1 = exp2f(fmaf((float)qa[4 + e], -INVQ, -riN - w1[e]));
        float a2 = exp2f(fmaf((float)qb[e], -INVQ, -riN - w2[e]));
        float a3 = exp2f(fmaf((float)qb[4 + e], -INVQ, -riN - w3[e]));
        asumN += a0 + a1 + a2 + a3;
        pk0.e[e] = f2bf(a0); pk0.e[4 + e] = f2bf(a1);
        pk1.e[e] = f2bf(a2); pk1.e[4 + e] = f2bf(a3);
      }
      *(u16x8*)&AT[rn * 128 + (cnp ^ swr)] = pk0.v;
      *(u16x8*)&AT[rn * 128 + ((cnp + 8) ^ swr)] = pk1.v;
    } else {
      bool anytr = false;
#pragma unroll
      for (int h = 0; h < 2; ++h) {
        const int Jb = kh * 64 + jc * 2 + h;
        if (Jb <= I) {
          const u16* blk = DqTri + triblk(I, Jb);
          u16x8 q = *(const u16x8*)&blk[rn * 64 + cnn];
          const float* wp = w + Jb * 64 + cnn;
          f32x4 w0 = *(const f32x4*)wp;
          f32x4 w1 = *(const f32x4*)(wp + 4);
          union { u16x8 v; u16 e[8]; } pk;
#pragma unroll
          for (int e = 0; e < 4; ++e) {
            float a0 = exp2f(fmaf((float)q[e], -INVQ, -riN - w0[e]));
            float a1 = exp2f(fmaf((float)q[4 + e], -INVQ, -riN - w1[e]));
            asumN += a0 + a1;
            pk.e[e] = f2bf(a0); pk.e[4 + e] = f2bf(a1);
          }
          *(u16x8*)&AT[rn * 128 + ((h * 64 + cnn) ^ swr)] = pk.v;
        } else {
          anytr = true;
          const u16* blk = DqTri + triblk(Jb, I);
          u16x8 q = *(const u16x8*)&blk[rn * 64 + cnn];
          *(u16x8*)&stg[h * 4096 + rn * 64 + (cnn ^ swr)] = q;
        }
      }
      if (anytr) {
        __syncthreads();
#pragma unroll
        for (int h = 0; h < 2; ++h) {
          const int Jb = kh * 64 + jc * 2 + h;
          if (Jb <= I) continue;
#pragma unroll
          for (int cc = 0; cc < 8; ++cc) {
            int sj = cc * 8 + sjg;
            u16 q = stg[h * 4096 + sj * 64 + (p ^ ((sj & 7) << 3))];
            float a = exp2f(fmaf((float)q, -INVQ, -riT - w[Jb * 64 + sj]));
            asumT += a;
            AT[p * 128 + ((h * 64 + sj) ^ swp)] = f2bf(a);
          }
        }
      }
    }
    __syncthreads();  // AT + Bs (gload drained) ready
#pragma unroll
    for (int ks = 0; ks < 4; ++ks) {
      bf16x8 a2[2], b2[4];
#pragma unroll
      for (int m = 0; m < 2; ++m) {
        int rl = wrg + m * 16 + fr;
        a2[m] = *(const bf16x8*)&AT[rl * 128 + ((ks * 32 + ko) ^ ((rl & 7) << 3))];
      }
#pragma unroll
      for (int n = 0; n < 4; ++n)
        b2[n] = *(const bf16x8*)&Bs[ks * 8192 + (wcg + n * 16 + fr) * 32 + ko];
#pragma unroll
      for (int m = 0; m < 2; ++m)
#pragma unroll
        for (int n = 0; n < 4; ++n)
          acc[m][n] = __builtin_amdgcn_mfma_f32_16x16x32_bf16(a2[m], b2[n], acc[m][n], 0, 0, 0);
    }
  }
  // write M partial
#pragma unroll
  for (int m = 0; m < 2; ++m)
#pragma unroll
    for (int n = 0; n < 4; ++n)
#pragma unroll
      for (int q = 0; q < 4; ++q) {
        int row = I * 64 + wrg + m * 16 + (lane >> 4) * 4 + q;
        int d = wcg + n * 16 + fr;
        Mout[(size_t)kh * 2097152 + (size_t)row * 256 + d] = acc[m][n][q];
      }
  // partial rowsum(A)
  SredN[rn][tid & 7] = asumN;
  SredT[p][sjg] = NEG ? asumT : 0.f;
  __syncthreads();
  if (tid < 64) {
    float s = 0.f;
#pragma unroll
    for (int b = 0; b < 8; ++b) s += SredN[tid][b] + SredT[tid][b];
    sout[kh * 8192 + I * 64 + tid] = s;
  }
}

// ---------- elementwise / transpose / norms ----------
__global__ void convert_split_k(const float* __restrict__ src, u16* __restrict__ hi,
                                u16* __restrict__ lo, int n) {
  int i = blockIdx.x * 256 + threadIdx.x;
  if (i < n) {
    float v = src[i];
    u16 h = f2bf(v);
    hi[i] = h;
    lo[i] = f2bf(v - bf2f(h));
  }
}

__global__ void transpose_split_k(const float* __restrict__ src, int K, int N,
                                  u16* __restrict__ hi, u16* __restrict__ lo) {
  __shared__ float t[32][33];
  int x = threadIdx.x & 31, y = threadIdx.x >> 5;
  int k0 = blockIdx.x * 32, n0 = blockIdx.y * 32;
  for (int yy = y; yy < 32; yy += 8) t[yy][x] = src[(size_t)(k0 + yy) * N + n0 + x];
  __syncthreads();
  for (int yy = y; yy < 32; yy += 8) {
    float v = t[x][yy];
    size_t idx = (size_t)(n0 + yy) * K + k0 + x;
    u16 h = f2bf(v);
    hi[idx] = h;
    lo[idx] = f2bf(v - bf2f(h));
  }
}

__global__ void transpose_b16_k(const float* __restrict__ src, int M, int D,
                                u16* __restrict__ dst) {
  __shared__ float t[32][33];
  int x = threadIdx.x & 31, y = threadIdx.x >> 5;
  int m0 = blockIdx.x * 32, d0 = blockIdx.y * 32;
  for (int yy = y; yy < 32; yy += 8) t[yy][x] = src[(size_t)(m0 + yy) * D + d0 + x];
  __syncthreads();
  for (int yy = y; yy < 32; yy += 8)
    dst[(size_t)(d0 + yy) * M + m0 + x] = f2bf(t[x][yy]);
}

__global__ void rownorm_k(const float* __restrict__ src, float* __restrict__ o) {
  int i = blockIdx.x, t = threadIdx.x;
  float s = 0.f;
  for (int d = t; d < 256; d += 64) {
    float v = src[(size_t)i * 256 + d];
    s += v * v;
  }
  for (int off = 32; off; off >>= 1) s += __shfl_down(s, off, 64);
  if (t == 0) o[i] = s;
}

__global__ void zero_k(float* __restrict__ p, int n) {
  int i = blockIdx.x * 256 + threadIdx.x;
  if (i < n) p[i] = 0.f;
}

__global__ void decode_k(float* __restrict__ out, float x, int n) {
  int i = blockIdx.x * 256 + threadIdx.x;
  if (i < n) out[i] = x;
}

__global__ void final_out_k(const float* __restrict__ M1, const float* __restrict__ M2,
                            const float* __restrict__ sp, const float* __restrict__ sn,
                            float* __restrict__ out) {
  __shared__ float S[256];
  int i = blockIdx.x, d = threadIdx.x;
  size_t idx = (size_t)i * 256 + d;
  float spv = sp[i] + sp[8192 + i];
  float snv = sn[i] + sn[8192 + i];
  float v = snv * (M1[idx] + M1[2097152 + idx]) - spv * (M2[idx] + M2[2097152 + idx]);
  S[d] = v * v;
  __syncthreads();
  for (int off = 128; off; off >>= 1) {
    if (d < off) S[d] += S[d + off];
    __syncthreads();
  }
  if (d == 0) out[i] = S[0];
}

// ---------- host ----------
extern "C" void kernel_launch(void* const* d_in, const int* in_sizes, int n_in,
                              void* d_out, int out_size, void* d_ws, size_t ws_size,
                              hipStream_t stream) {
  (void)in_sizes; (void)n_in; (void)out_size;
  const float* pos = (const float*)d_in[0];
  const float* z   = (const float*)d_in[1];
  const float* W1  = (const float*)d_in[2];
  const float* b1  = (const float*)d_in[3];
  const float* W2  = (const float*)d_in[4];
  const float* b2  = (const float*)d_in[5];
  const float* W3  = (const float*)d_in[6];
  const float* b3  = (const float*)d_in[7];
  const float* W4  = (const float*)d_in[8];
  const float* b4  = (const float*)d_in[9];
  const float* W5  = (const float*)d_in[10];
  const float* b5  = (const float*)d_in[11];
  float* out = (float*)d_out;

  if (ws_size < (size_t)261500000) {
    decode_k<<<32, 256, 0, stream>>>(out, (float)(double)(ws_size >> 10), 8192);
    return;
  }

  char* wsp = (char*)d_ws;
  size_t off = 0;
  auto alloc = [&](size_t bytes) -> char* {
    char* p = wsp + off;
    off += (bytes + 255) & ~(size_t)255;
    return p;
  };
  u16* DqPos = (u16*)alloc((size_t)8192 * 8192 * 2);  // 134.2 MB
  u16* DqTri = (u16*)alloc((size_t)8256 * 4096 * 2);  // 67.6 MB (lower block-triangle)
  u16* Yh    = (u16*)alloc((size_t)16384 * 256 * 2);  // pos rows [0:8192), gen [8192:)
  u16* Yl    = (u16*)alloc((size_t)16384 * 256 * 2);
  u16* posT  = (u16*)alloc((size_t)256 * 8192 * 2);
  u16* genT  = (u16*)alloc((size_t)256 * 8192 * 2);
  float* yN2 = (float*)alloc(16384 * 4);
  float* rv  = (float*)alloc(8192 * 4);
  float* cpos = (float*)alloc(8192 * 4);
  float* cneg = (float*)alloc(8192 * 4);
  float* spv = (float*)alloc(2 * 8192 * 4);
  float* snv = (float*)alloc(2 * 8192 * 4);
  float* M1  = (float*)alloc((size_t)2 * 8192 * 256 * 4);  // K-split partials (16.8 MB)
  float* M2  = (float*)alloc((size_t)2 * 8192 * 256 * 4);
  // Pm/Ps (PSLOTS x 8192 f32 = 2.62 MB each) alias M1: dead before pv_k writes M1
  float* Pm = M1;
  float* Ps = Pm + (size_t)PSLOTS * 8192;

  // transient MLP arena aliases DqPos (~94 MB < 134 MB; dead before DqPos written)
  size_t toff = 0;
  char* tbase = (char*)DqPos;
  auto talloc = [&](size_t bytes) -> char* {
    char* p = tbase + toff;
    toff += (bytes + 255) & ~(size_t)255;
    return p;
  };
  u16* zh    = (u16*)talloc((size_t)8192 * 128 * 2);
  u16* zl    = (u16*)talloc((size_t)8192 * 128 * 2);
  u16* W1Th  = (u16*)talloc(1024 * 128 * 2);
  u16* W1Tl  = (u16*)talloc(1024 * 128 * 2);
  u16* W2Th  = (u16*)talloc(1024 * 1024 * 2);
  u16* W2Tl  = (u16*)talloc(1024 * 1024 * 2);
  u16* W3Th  = (u16*)talloc(1024 * 1024 * 2);
  u16* W3Tl  = (u16*)talloc(1024 * 1024 * 2);
  u16* W4Th  = (u16*)talloc(1024 * 1024 * 2);
  u16* W4Tl  = (u16*)talloc(1024 * 1024 * 2);
  u16* W5Th  = (u16*)talloc(256 * 1024 * 2);
  u16* W5Tl  = (u16*)talloc(256 * 1024 * 2);
  u16* h1h   = (u16*)talloc((size_t)8192 * 1024 * 2);
  u16* h1l   = (u16*)talloc((size_t)8192 * 1024 * 2);
  u16* h2h   = (u16*)talloc((size_t)8192 * 1024 * 2);
  u16* h2l   = (u16*)talloc((size_t)8192 * 1024 * 2);
  float* genf = (float*)talloc((size_t)8192 * 256 * 4);

  u16* genH = Yh + (size_t)8192 * 256;
  u16* genL = Yl + (size_t)8192 * 256;
  float* pN2 = yN2;
  float* gN2 = yN2 + 8192;

  // ---- preprocessing ----
  convert_split_k<<<4096, 256, 0, stream>>>(z, zh, zl, 8192 * 128);
  convert_split_k<<<8192, 256, 0, stream>>>(pos, Yh, Yl, 8192 * 256);
  transpose_split_k<<<dim3(4, 32), 256, 0, stream>>>(W1, 128, 1024, W1Th, W1Tl);
  transpose_split_k<<<dim3(32, 32), 256, 0, stream>>>(W2, 1024, 1024, W2Th, W2Tl);
  transpose_split_k<<<dim3(32, 32), 256, 0, stream>>>(W3, 1024, 1024, W3Th, W3Tl);
  transpose_split_k<<<dim3(32, 32), 256, 0, stream>>>(W4, 1024, 1024, W4Th, W4Tl);
  transpose_split_k<<<dim3(32, 8), 256, 0, stream>>>(W5, 1024, 256, W5Th, W5Tl);
  rownorm_k<<<8192, 64, 0, stream>>>(pos, pN2);
  transpose_b16_k<<<dim3(256, 8), 256, 0, stream>>>(pos, 8192, 256, posT);

  // ---- MLP (split-bf16, fused bias+selu; 64x128 tiles for occupancy) ----
  gemm_k<64, 128, 2, 2, EPI_MLP><<<dim3(8, 128), 256, 0, stream>>>(
      zh, zl, 128, W1Th, W1Tl, 128, 128, nullptr, 0, b1, 1, h1h, h1l, 1024,
      nullptr, nullptr, nullptr);
  gemm_k<64, 128, 2, 2, EPI_MLP><<<dim3(8, 128), 256, 0, stream>>>(
      h1h, h1l, 1024, W2Th, W2Tl, 1024, 1024, nullptr, 0, b2, 1, h2h, h2l, 1024,
      nullptr, nullptr, nullptr);
  gemm_k<64, 128, 2, 2, EPI_MLP><<<dim3(8, 128), 256, 0, stream>>>(
      h2h, h2l, 1024, W3Th, W3Tl, 1024, 1024, nullptr, 0, b3, 1, h1h, h1l, 1024,
      nullptr, nullptr, nullptr);
  gemm_k<64, 128, 2, 2, EPI_MLP><<<dim3(8, 128), 256, 0, stream>>>(
      h1h, h1l, 1024, W4Th, W4Tl, 1024, 1024, nullptr, 0, b4, 1, h2h, h2l, 1024,
      nullptr, nullptr, nullptr);
  gemm_k<64, 128, 2, 2, EPI_MLP><<<dim3(2, 128), 256, 0, stream>>>(
      h2h, h2l, 1024, W5Th, W5Tl, 1024, 1024, genf, 256, b5, 0,
      genH, genL, 256, nullptr, nullptr, nullptr);

  rownorm_k<<<8192, 64, 0, stream>>>(genf, gN2);
  transpose_b16_k<<<dim3(256, 8), 256, 0, stream>>>(genf, 8192, 256, genT);

  // ---- build stored distance matrices (un-fused; transients dead) ----
  gemm_k<128, 128, 2, 2, EPI_DISTQ><<<4096, 256, 0, stream>>>(
      genH, genL, 256, Yh, Yl, 256, 256, nullptr, 0, nullptr, 0, nullptr,
      nullptr, 0, gN2, pN2, DqPos);
  gemm_k<128, 128, 2, 2, EPI_NEGTRI><<<2080, 256, 0, stream>>>(
      genH, genL, 256, genH, genL, 256, 256, nullptr, 0, nullptr, 0, nullptr,
      nullptr, 0, gN2, gN2, DqTri);

  // ---- Sinkhorn (log2 domain): 5 x {row, col}, occupancy-tuned grids ----
  zero_k<<<64, 256, 0, stream>>>(cpos, 16384);  // cpos + cneg (contiguous)
  for (int it = 0; it < 5; ++it) {
    sink_k<<<dim3(8, 128), 256, 0, stream>>>(DqPos, DqTri, cpos, cneg, Pm, Ps);
    comb_rv_k<<<32, 256, 0, stream>>>(Pm, Ps, rv);
    colpass_k<<<1536, 256, 0, stream>>>(DqPos, DqTri, rv, Pm, Ps);
    comb_cpc_k<<<64, 256, 0, stream>>>(Pm, Ps, cpos, cneg);
  }

  // ---- PV from stored Dq (K-split x2, partial M/s) ----
  pv_k<false><<<dim3(2, 128), 512, 0, stream>>>(DqPos, DqTri, rv, cpos, posT, M1, spv);
  pv_k<true><<<dim3(2, 128), 512, 0, stream>>>(DqPos, DqTri, rv, cneg, genT, M2, snv);

  // ---- out_i = sum_d (sn_i*(M1a+M1b) - sp_i*(M2a+M2b))^2 ----
  final_out_k<<<8192, 256, 0, stream>>>(M1, M2, spv, snv, out);
}